// Round 10
// baseline (554.746 us; speedup 1.0000x reference)
//
#include <hip/hip_runtime.h>

#define S_LEN 2048
#define DMODEL 512
#define QS 0.12751742795f   // (1/sqrt(128)) * log2(e)

typedef __attribute__((ext_vector_type(8))) short bf16x8;
typedef __attribute__((ext_vector_type(4))) float f32x4;
typedef __attribute__((ext_vector_type(4))) unsigned short u16x4;
typedef __attribute__((ext_vector_type(8))) unsigned short u16x8;
typedef __attribute__((ext_vector_type(2))) unsigned int u32x2;

__device__ __forceinline__ unsigned short f2bf(float f) {
    unsigned int u = __float_as_uint(f);
    u += 0x7fff + ((u >> 16) & 1);            // RNE
    return (unsigned short)(u >> 16);
}
__device__ __forceinline__ float bf2f(unsigned short h) {
    return __uint_as_float(((unsigned int)h) << 16);
}
__device__ __forceinline__ unsigned int cvtpk(float lo, float hi) {
    unsigned int r;
    asm("v_cvt_pk_bf16_f32 %0, %1, %2" : "=v"(r) : "v"(lo), "v"(hi));
    return r;
}
__device__ __forceinline__ void gll16(const void* g, void* l) {
    __builtin_amdgcn_global_load_lds(
        (const __attribute__((address_space(1))) unsigned int*)g,
        (__attribute__((address_space(3))) unsigned int*)l, 16, 0, 0);
}

// ---------------- fp32 -> bf16 bulk convert (all 4 weight tensors, 1 launch) ----------------
__global__ __launch_bounds__(256) void conv_all(
    const float4* __restrict__ in_w, const float4* __restrict__ out_w,
    const float4* __restrict__ ff1_w, const float4* __restrict__ ff2_w,
    u16x4* __restrict__ in_wb, u16x4* __restrict__ out_wb,
    u16x4* __restrict__ ff1_wb, u16x4* __restrict__ ff2_wb)
{
    int i = blockIdx.x * 256 + threadIdx.x;
    const float4* src; u16x4* dst; int j;
    if (i < 589824)        { src = in_w;  dst = in_wb;  j = i; }
    else if (i < 786432)   { src = out_w; dst = out_wb; j = i - 589824; }
    else if (i < 1572864)  { src = ff1_w; dst = ff1_wb; j = i - 786432; }
    else                   { src = ff2_w; dst = ff2_wb; j = i - 1572864; }
    float4 v = src[j];
    u16x4 o = { f2bf(v.x), f2bf(v.y), f2bf(v.z), f2bf(v.w) };
    dst[j] = o;
}

// ---------------- embedding + positional encoding ----------------
__global__ __launch_bounds__(256) void embed_kernel(
    const float* __restrict__ src, const float* __restrict__ ew,
    const float* __restrict__ eb, float* __restrict__ X,
    unsigned short* __restrict__ Xb)
{
    int rid = blockIdx.x;              // b*S + s
    int s = rid & (S_LEN - 1);
    int tid = threadIdx.x;
    __shared__ float sr[25];
    if (tid < 25) sr[tid] = src[rid * 25 + tid];
    __syncthreads();
    #pragma unroll
    for (int rep = 0; rep < 2; rep++) {
        int d = tid + rep * 256;
        float a = eb[d];
        #pragma unroll
        for (int k = 0; k < 25; k++) a = fmaf(sr[k], ew[d * 25 + k], a);
        int i2 = d & ~1;
        float div = expf(-(float)i2 * (9.210340371976184f / 512.f));
        float ang = (float)s * div;
        a += (d & 1) ? cosf(ang) : sinf(ang);
        X[(size_t)rid * DMODEL + d] = a;
        Xb[(size_t)rid * DMODEL + d] = f2bf(a);
    }
}

// ---------------- bf16 MFMA GEMM: C = A @ W^T + bias ----------------
// Double-buffered LDS pipeline (round-9 measured-best). MODE 3 additionally
// pre-scales Q columns (colb<512) by QS for the exp2-domain flash softmax.
template<int MODE, int BN>
__global__ __launch_bounds__(256) void gemm_bf16(
    const unsigned short* __restrict__ A, int lda,
    const unsigned short* __restrict__ W, int K,
    const float* __restrict__ bias,
    unsigned short* __restrict__ out, int ldc,
    unsigned short* __restrict__ out2)
{
    constexpr int NJ = BN / 32;
    __shared__ __align__(16) unsigned short As[2][128 * 64];
    __shared__ __align__(16) unsigned short Ws[2][BN * 64];
    int tid = threadIdx.x;
    int lane = tid & 63, w = tid >> 6;
    int g = lane >> 4, c15 = lane & 15;
    int wm = w >> 1, wn = w & 1;
    int bm, bn;
    if (BN == 64) {
        int raw = blockIdx.x;
        int lid = ((raw & 7) << 6) | (raw >> 3);  // consecutive lid -> same XCD
        bn = lid & 7; bm = lid >> 3;
    } else {
        bm = blockIdx.y; bn = blockIdx.x;
    }

    f32x4 acc[4][NJ];
    #pragma unroll
    for (int i = 0; i < 4; i++)
        #pragma unroll
        for (int j = 0; j < NJ; j++) acc[i][j] = (f32x4){0.f, 0.f, 0.f, 0.f};

    auto stage = [&](int kk, int bi) {
        #pragma unroll
        for (int i = 0; i < 4; i++) {
            int chunk = tid + i * 256;
            int r = chunk >> 3, c = chunk & 7;
            int cs = c ^ (r & 7);
            gll16(A + (size_t)(bm * 128 + r) * lda + kk * 64 + cs * 8,
                  (void*)(As[bi] + chunk * 8));
        }
        #pragma unroll
        for (int i = 0; i < BN / 32; i++) {
            int chunk = tid + i * 256;
            int r = chunk >> 3, c = chunk & 7;
            int cs = c ^ (r & 7);
            gll16(W + (size_t)(bn * BN + r) * K + kk * 64 + cs * 8,
                  (void*)(Ws[bi] + chunk * 8));
        }
    };

    const int nk = K >> 6;
    stage(0, 0);
    __syncthreads();          // drain prologue staging
    int buf = 0;

    for (int kk = 0; kk < nk; kk++) {
        if (kk + 1 < nk) stage(kk + 1, buf ^ 1);   // prefetch overlaps compute
        bf16x8 a[4][2], b[NJ][2];
        #pragma unroll
        for (int mi = 0; mi < 4; mi++) {
            int row = wm * 64 + mi * 16 + c15;
            #pragma unroll
            for (int h = 0; h < 2; h++) {
                int ck = (h * 4 + g) ^ (row & 7);
                a[mi][h] = *(const bf16x8*)((const char*)As[buf] + row * 128 + ck * 16);
            }
        }
        #pragma unroll
        for (int nj = 0; nj < NJ; nj++) {
            int row = wn * (BN / 2) + nj * 16 + c15;
            #pragma unroll
            for (int h = 0; h < 2; h++) {
                int ck = (h * 4 + g) ^ (row & 7);
                b[nj][h] = *(const bf16x8*)((const char*)Ws[buf] + row * 128 + ck * 16);
            }
        }
        __builtin_amdgcn_s_setprio(1);
        #pragma unroll
        for (int h = 0; h < 2; h++)
            #pragma unroll
            for (int mi = 0; mi < 4; mi++)
                #pragma unroll
                for (int nj = 0; nj < NJ; nj++)
                    acc[mi][nj] = __builtin_amdgcn_mfma_f32_16x16x32_bf16(
                        a[mi][h], b[nj][h], acc[mi][nj], 0, 0, 0);
        __builtin_amdgcn_s_setprio(0);
        __syncthreads();      // drains prefetch vmcnt + buffer handoff
        buf ^= 1;
    }
    #pragma unroll
    for (int nj = 0; nj < NJ; nj++) {
        int colb = bn * BN + wn * (BN / 2) + nj * 16;
        float bv = bias[colb + c15];
        #pragma unroll
        for (int mi = 0; mi < 4; mi++) {
            int rowb = bm * 128 + wm * 64 + mi * 16 + g * 4;
            if (MODE == 3 && colb >= 1024) {     // V -> transposed global
                int cv = colb - 1024 + c15;
                int hh = cv >> 7, d = cv & 127;
                int bb = rowb >> 11, t = rowb & (S_LEN - 1);
                u16x4 pk;
                #pragma unroll
                for (int r = 0; r < 4; r++) pk[r] = f2bf(acc[mi][nj][r] + bv);
                *(u16x4*)(out2 + ((size_t)(bb * 4 + hh) * 128 + d) * S_LEN + t) = pk;
            } else {
                #pragma unroll
                for (int r = 0; r < 4; r++) {
                    float v = acc[mi][nj][r] + bv;
                    if (MODE == 2) v = fmaxf(v, 0.f);
                    if (MODE == 3 && colb < 512) v *= QS;   // pre-scale Q
                    out[(size_t)(rowb + r) * ldc + colb + c15] = f2bf(v);
                }
            }
        }
    }
}

// ---------------- bf16 MFMA flash attention (exp2 domain, uniform split-K) ----------------
// Per (b,h), 68 work items: qb 0-9 direct; qb 10-19 2 chunks; 20-29 3; 30-31 4.
// All chunks <= 20 KV-tiles -> balanced makespan. 1088 blocks total.
__global__ __launch_bounds__(256) void flash_attn(
    const unsigned short* __restrict__ QKb,
    const unsigned short* __restrict__ Vt,
    unsigned short* __restrict__ Ob,
    unsigned short* __restrict__ Opart,   // [928][64*128] bf16
    float* __restrict__ Mpart,            // [928][64]
    float* __restrict__ Lpart)            // [928][64]
{
    __shared__ __align__(16) unsigned short Ks[2][32 * 128];
    __shared__ __align__(16) unsigned short Vts[2][128 * 32];
    __shared__ __align__(16) unsigned short Plds[4][16 * 40];   // stride 40 u16
    int tid = threadIdx.x;
    int lane = tid & 63, w = tid >> 6;
    int g = lane >> 4, c15 = lane & 15;
    int raw = blockIdx.x;
    int lid = (raw & 7) * 136 + (raw >> 3);      // XCD-chunked (1088 = 8*136)
    int bh = lid / 68, idx = lid - bh * 68;
    int b = bh >> 2, h = bh & 3;
    int qb, j, nc;
    if (idx < 10)      { qb = idx; j = 0; nc = 1; }
    else if (idx < 30) { int s = idx - 10; qb = 10 + (s >> 1); j = s & 1; nc = 2; }
    else if (idx < 60) { int s = idx - 30; qb = 20 + s / 3;    j = s - (qb - 20) * 3; nc = 3; }
    else               { int s = idx - 60; qb = 30 + (s >> 2); j = s & 3; nc = 4; }
    int T = 2 * qb + 2;
    int kt0 = j * T / nc;
    int nkt = (j + 1) * T / nc - kt0;
    int split;
    if (nc == 1) split = -1;
    else {
        int off = (qb < 20) ? 2 * (qb - 10) : (qb < 30 ? 20 + 3 * (qb - 20) : 50 + 4 * (qb - 30));
        split = bh * 58 + off + j;
    }

    // Q fragments (B-operand, pre-scaled by QS): q-row = qb*64 + w*16 + c15
    bf16x8 q[4];
    {
        const unsigned short* qrow =
            QKb + (size_t)(b * S_LEN + qb * 64 + w * 16 + c15) * 1024 + h * 128;
        #pragma unroll
        for (int k0 = 0; k0 < 4; k0++) q[k0] = *(const bf16x8*)(qrow + k0 * 32 + g * 8);
    }
    f32x4 o[8];
    #pragma unroll
    for (int cd = 0; cd < 8; cd++) o[cd] = (f32x4){0.f, 0.f, 0.f, 0.f};
    float m = -3e38f, l = 0.f;

    auto stage = [&](int kt, int bi) {
        #pragma unroll
        for (int i = 0; i < 2; i++) {      // K tile: 32 rows x 16 chunks (swizzled src)
            int chunk = tid + i * 256;
            int r = chunk >> 4, c = chunk & 15;
            int cs = (c & 8) | ((c ^ r) & 7);
            gll16(QKb + (size_t)(b * S_LEN + kt * 32 + r) * 1024 + 512 + h * 128 + cs * 8,
                  (void*)(Ks[bi] + chunk * 8));
        }
        #pragma unroll
        for (int i = 0; i < 2; i++) {      // Vt tile: 128 rows x 4 chunks
            int chunk = tid + i * 256;
            int r = chunk >> 2, c = chunk & 3;
            int cs = (c ^ r) & 3;
            gll16(Vt + ((size_t)(b * 4 + h) * 128 + r) * S_LEN + kt * 32 + cs * 8,
                  (void*)(Vts[bi] + chunk * 8));
        }
    };

    stage(kt0, 0);
    __syncthreads();          // drains vmcnt(0) + barrier
    int buf = 0;

    for (int t = 0; t < nkt; t++) {
        int kt = kt0 + t;
        if (t + 1 < nkt) stage(kt + 1, buf ^ 1);   // prefetch overlaps compute
        // --- S^T = K Q^T (swapped): lane holds q-row c15, tokens c*16+g*4+r ---
        f32x4 sf[2];
        __builtin_amdgcn_s_setprio(1);
        #pragma unroll
        for (int c = 0; c < 2; c++) {
            sf[c] = (f32x4){0.f, 0.f, 0.f, 0.f};
            int tok16 = c * 16 + c15;
            #pragma unroll
            for (int k0 = 0; k0 < 4; k0++) {
                int ck = k0 * 4 + g;
                int cs = (ck & 8) | ((ck ^ tok16) & 7);
                bf16x8 kf = *(const bf16x8*)((const char*)Ks[buf] + tok16 * 256 + cs * 16);
                sf[c] = __builtin_amdgcn_mfma_f32_16x16x32_bf16(kf, q[k0], sf[c], 0, 0, 0);
            }
        }
        __builtin_amdgcn_s_setprio(0);
        // --- mask: last two tiles only (incl. PRE block) ---
        if (kt >= 2 * qb) {
            int qr = qb * 64 + w * 16 + c15;
            #pragma unroll
            for (int c = 0; c < 2; c++)
                #pragma unroll
                for (int r = 0; r < 4; r++) {
                    int tok = kt * 32 + c * 16 + g * 4 + r;
                    bool ok = (tok <= qr) || (qr < 20 && tok < 20);
                    if (!ok) sf[c][r] = -3e38f;
                }
        }
        // --- row max: in-lane tree + 2 shfl (log2 domain) ---
        float t0 = fmaxf(fmaxf(sf[0][0], sf[0][1]), fmaxf(sf[0][2], sf[0][3]));
        float t1 = fmaxf(fmaxf(sf[1][0], sf[1][1]), fmaxf(sf[1][2], sf[1][3]));
        float mt = fmaxf(t0, t1);
        mt = fmaxf(mt, __shfl_xor(mt, 16));
        mt = fmaxf(mt, __shfl_xor(mt, 32));
        // --- defer-max (T13): 8 nats = 11.54 bits ---
        bool need = !__all(mt <= m + 11.5f);
        float sc = 1.f;
        if (need) {
            float mn = fmaxf(m, mt);
            sc = __builtin_amdgcn_exp2f(m - mn);
            m = mn;
        }
        #pragma unroll
        for (int c = 0; c < 2; c++)
            #pragma unroll
            for (int r = 0; r < 4; r++)
                sf[c][r] = __builtin_amdgcn_exp2f(sf[c][r] - m);
        float s0 = (sf[0][0] + sf[0][1]) + (sf[0][2] + sf[0][3]);
        float s1 = (sf[1][0] + sf[1][1]) + (sf[1][2] + sf[1][3]);
        float ls = s0 + s1;
        ls += __shfl_xor(ls, 16);
        ls += __shfl_xor(ls, 32);
        if (need) l *= sc;
        l += ls;
        // --- P -> Plds via v_cvt_pk_bf16_f32 (T12), packed b64 writes ---
        #pragma unroll
        for (int c = 0; c < 2; c++) {
            u32x2 pk = { cvtpk(sf[c][0], sf[c][1]), cvtpk(sf[c][2], sf[c][3]) };
            *(u32x2*)&Plds[w][c15 * 40 + c * 16 + g * 4] = pk;
        }
        // --- rescale O (skipped when deferred) ---
        if (need) {
            float r0 = __shfl(sc, g * 4 + 0);
            float r1 = __shfl(sc, g * 4 + 1);
            float r2 = __shfl(sc, g * 4 + 2);
            float r3 = __shfl(sc, g * 4 + 3);
            #pragma unroll
            for (int cd = 0; cd < 8; cd++) {
                o[cd][0] *= r0; o[cd][1] *= r1; o[cd][2] *= r2; o[cd][3] *= r3;
            }
        }
        // --- O += P V (single K=32 MFMA per d-group) ---
        bf16x8 pa = *(const bf16x8*)((const char*)&Plds[w][0] + c15 * 80 + g * 16);
        __builtin_amdgcn_s_setprio(1);
        #pragma unroll
        for (int cd = 0; cd < 8; cd++) {
            int dv = cd * 16 + c15;
            int cs = (g ^ dv) & 3;
            bf16x8 vf = *(const bf16x8*)((const char*)Vts[buf] + dv * 64 + cs * 16);
            o[cd] = __builtin_amdgcn_mfma_f32_16x16x32_bf16(pa, vf, o[cd], 0, 0, 0);
        }
        __builtin_amdgcn_s_setprio(0);
        __syncthreads();      // drains prefetch vmcnt + buffer handoff
        buf ^= 1;
    }

    if (split < 0) {
        float li0 = 1.f / __shfl(l, g * 4 + 0);
        float li1 = 1.f / __shfl(l, g * 4 + 1);
        float li2 = 1.f / __shfl(l, g * 4 + 2);
        float li3 = 1.f / __shfl(l, g * 4 + 3);
        size_t obase = (size_t)(b * S_LEN + qb * 64 + w * 16 + g * 4) * 512 + h * 128;
        #pragma unroll
        for (int cd = 0; cd < 8; cd++) {
            Ob[obase + 0 * 512 + cd * 16 + c15] = f2bf(o[cd][0] * li0);
            Ob[obase + 1 * 512 + cd * 16 + c15] = f2bf(o[cd][1] * li1);
            Ob[obase + 2 * 512 + cd * 16 + c15] = f2bf(o[cd][2] * li2);
            Ob[obase + 3 * 512 + cd * 16 + c15] = f2bf(o[cd][3] * li3);
        }
    } else {
        unsigned short* op = Opart + (size_t)split * 8192;
        int rb = w * 16 + g * 4;
        #pragma unroll
        for (int cd = 0; cd < 8; cd++) {
            op[(rb + 0) * 128 + cd * 16 + c15] = f2bf(o[cd][0]);
            op[(rb + 1) * 128 + cd * 16 + c15] = f2bf(o[cd][1]);
            op[(rb + 2) * 128 + cd * 16 + c15] = f2bf(o[cd][2]);
            op[(rb + 3) * 128 + cd * 16 + c15] = f2bf(o[cd][3]);
        }
        if (g == 0) {
            Mpart[split * 64 + w * 16 + c15] = m;
            Lpart[split * 64 + w * 16 + c15] = l;
        }
    }
}

// ---------------- merge split-K partials (qb 10..31, 2-4 parts) ----------------
__global__ __launch_bounds__(256) void attn_merge(
    const unsigned short* __restrict__ Opart,
    const float* __restrict__ Mpart, const float* __restrict__ Lpart,
    unsigned short* __restrict__ Ob)
{
    int bid = blockIdx.x;                 // bh*22 + (qb-10)
    int bh = bid / 22, qe = bid - bh * 22;
    int qb = 10 + qe;
    int b = bh >> 2, h = bh & 3;
    int nc = (qb < 20) ? 2 : (qb < 30 ? 3 : 4);
    int off = (qb < 20) ? 2 * (qb - 10) : (qb < 30 ? 20 + 3 * (qb - 20) : 50 + 4 * (qb - 30));
    int p0 = bh * 58 + off;
    int t = threadIdx.x;
    int r = t >> 2, dq = t & 3;
    float mi[4], li[4], wi[4];
    #pragma unroll
    for (int i = 0; i < 4; i++) {
        mi[i] = (i < nc) ? Mpart[(p0 + i) * 64 + r] : -3e38f;
        li[i] = (i < nc) ? Lpart[(p0 + i) * 64 + r] : 0.f;
    }
    float ms = fmaxf(fmaxf(mi[0], mi[1]), fmaxf(mi[2], mi[3]));
    float lsum = 0.f;
    #pragma unroll
    for (int i = 0; i < 4; i++) {
        wi[i] = (i < nc) ? __builtin_amdgcn_exp2f(mi[i] - ms) : 0.f;
        lsum += li[i] * wi[i];
    }
    float linv = 1.f / lsum;
    #pragma unroll
    for (int i = 0; i < 4; i++) wi[i] *= linv;
    unsigned short* od = Ob + (size_t)(b * S_LEN + qb * 64 + r) * 512 + h * 128 + dq * 32;
    size_t obase = (size_t)p0 * 8192 + r * 128 + dq * 32;
    #pragma unroll
    for (int i = 0; i < 4; i++) {
        u16x8 d;
        float acc[8];
        #pragma unroll
        for (int jj = 0; jj < 8; jj++) acc[jj] = 0.f;
        #pragma unroll
        for (int p = 0; p < 4; p++) {
            if (p < nc) {
                u16x8 a = *(const u16x8*)(Opart + obase + (size_t)p * 8192 + i * 8);
                #pragma unroll
                for (int jj = 0; jj < 8; jj++) acc[jj] += bf2f(a[jj]) * wi[p];
            }
        }
        #pragma unroll
        for (int jj = 0; jj < 8; jj++) d[jj] = f2bf(acc[jj]);
        *(u16x8*)(od + i * 8) = d;
    }
}

// ---------------- X = LayerNorm(X + D)*g + b ;  Xb = bf16(X) ----------------
__global__ __launch_bounds__(256) void add_ln_kernel(
    float* __restrict__ X, const unsigned short* __restrict__ D,
    const float* __restrict__ gw, const float* __restrict__ bw,
    unsigned short* __restrict__ Xb)
{
    int row = blockIdx.x;
    int tid = threadIdx.x;
    size_t base = (size_t)row * DMODEL;
    float v0 = X[base + tid] + bf2f(D[base + tid]);
    float v1 = X[base + tid + 256] + bf2f(D[base + tid + 256]);
    float s = v0 + v1;
    float sq = v0 * v0 + v1 * v1;
    #pragma unroll
    for (int off = 32; off > 0; off >>= 1) {
        s  += __shfl_down(s, off);
        sq += __shfl_down(sq, off);
    }
    __shared__ float red[2][4];
    int wv = tid >> 6;
    if ((tid & 63) == 0) { red[0][wv] = s; red[1][wv] = sq; }
    __syncthreads();
    s  = red[0][0] + red[0][1] + red[0][2] + red[0][3];
    sq = red[1][0] + red[1][1] + red[1][2] + red[1][3];
    float mu = s * (1.f / DMODEL);
    float var = sq * (1.f / DMODEL) - mu * mu;
    float rs = rsqrtf(var + 1e-5f);
    float y0 = (v0 - mu) * rs * gw[tid] + bw[tid];
    float y1 = (v1 - mu) * rs * gw[tid + 256] + bw[tid + 256];
    X[base + tid] = y0;
    X[base + tid + 256] = y1;
    Xb[base + tid] = f2bf(y0);
    Xb[base + tid + 256] = f2bf(y1);
}

// ---------------- out = tanh(X @ dec_w^T + dec_b) * 10 ----------------
__global__ __launch_bounds__(256) void decoder_kernel(
    const float* __restrict__ X, const float* __restrict__ w,
    const float* __restrict__ bias, float* __restrict__ out)
{
    int tid = threadIdx.x;
    int lane = tid & 63;
    int row = blockIdx.x * 4 + (tid >> 6);
    float s = 0.f;
    size_t base = (size_t)row * DMODEL;
    #pragma unroll
    for (int i = 0; i < 8; i++) s = fmaf(X[base + lane + i * 64], w[lane + i * 64], s);
    #pragma unroll
    for (int off = 32; off > 0; off >>= 1) s += __shfl_down(s, off);
    if (lane == 0) out[row] = tanhf(s + bias[0]) * 10.0f;
}

extern "C" void kernel_launch(void* const* d_in, const int* in_sizes, int n_in,
                              void* d_out, int out_size, void* d_ws, size_t ws_size,
                              hipStream_t stream)
{
    const float* src   = (const float*)d_in[0];
    const float* emb_w = (const float*)d_in[1];
    const float* emb_b = (const float*)d_in[2];
    const float* in_w  = (const float*)d_in[3];
    const float* in_b  = (const float*)d_in[4];
    const float* out_w = (const float*)d_in[5];
    const float* out_b = (const float*)d_in[6];
    const float* ln1_g = (const float*)d_in[7];
    const float* ln1_b = (const float*)d_in[8];
    const float* ln2_g = (const float*)d_in[9];
    const float* ln2_b = (const float*)d_in[10];
    const float* ff1_w = (const float*)d_in[11];
    const float* ff1_b = (const float*)d_in[12];
    const float* ff2_w = (const float*)d_in[13];
    const float* ff2_b = (const float*)d_in[14];
    const float* dec_w = (const float*)d_in[15];
    const float* dec_b = (const float*)d_in[16];

    char* ws = (char*)d_ws;
    float*          X   = (float*)ws;                              // 16 MB
    unsigned short* Xb  = (unsigned short*)(ws + (16u << 20));     //  8 MB
    unsigned short* Pb  = (unsigned short*)(ws + (24u << 20));     //  8 MB
    unsigned short* Ob  = (unsigned short*)(ws + (32u << 20));     //  8 MB
    unsigned short* QKb = (unsigned short*)(ws + (40u << 20));     // 16 MB
    unsigned short* Vt  = (unsigned short*)(ws + (56u << 20));     //  8 MB
    unsigned short* Hb  = (unsigned short*)(ws + (40u << 20));     // 32 MB (overlaps QKb+Vt)
    // Attention split-K partials overlay DEAD regions during flash+merge:
    // Opart (14.5 MB) over Xb + Pb-head; Mpart/Lpart at 31 MB (Pb tail).
    unsigned short* Opart = (unsigned short*)(ws + (16u << 20));   // 928*8192 bf16
    float* Mpart = (float*)(ws + (31u << 20));                     // 928*64 f32
    float* Lpart = Mpart + 928 * 64;
    unsigned short* in_wb  = (unsigned short*)(ws + (72u << 20));
    unsigned short* out_wb = in_wb  + 3u * 1536 * 512;
    unsigned short* ff1_wb = out_wb + 3u * 512 * 512;
    unsigned short* ff2_wb = ff1_wb + 3u * 2048 * 512;
    float* outp = (float*)d_out;
    const int M = 4 * S_LEN;   // 8192

    conv_all<<<9216, 256, 0, stream>>>(
        (const float4*)in_w, (const float4*)out_w,
        (const float4*)ff1_w, (const float4*)ff2_w,
        (u16x4*)in_wb, (u16x4*)out_wb, (u16x4*)ff1_wb, (u16x4*)ff2_wb);

    embed_kernel<<<M, 256, 0, stream>>>(src, emb_w, emb_b, X, Xb);

    for (int l = 0; l < 3; l++) {
        gemm_bf16<3, 128><<<dim3(12, 64), 256, 0, stream>>>(
            Xb, 512, in_wb + (size_t)l * 1536 * 512, 512, in_b + l * 1536,
            QKb, 1024, Vt);
        flash_attn<<<1088, 256, 0, stream>>>(QKb, Vt, Ob, Opart, Mpart, Lpart);
        attn_merge<<<352, 256, 0, stream>>>(Opart, Mpart, Lpart, Ob);
        gemm_bf16<1, 64><<<dim3(512), 256, 0, stream>>>(
            Ob, 512, out_wb + (size_t)l * 512 * 512, 512, out_b + l * 512,
            Pb, 512, nullptr);
        add_ln_kernel<<<M, 256, 0, stream>>>(X, Pb, ln1_g + l * 512, ln1_b + l * 512, Xb);
        gemm_bf16<2, 128><<<dim3(16, 64), 256, 0, stream>>>(
            Xb, 512, ff1_wb + (size_t)l * 2048 * 512, 512, ff1_b + l * 2048,
            Hb, 2048, nullptr);
        gemm_bf16<1, 64><<<dim3(512), 256, 0, stream>>>(
            Hb, 2048, ff2_wb + (size_t)l * 512 * 2048, 2048, ff2_b + l * 512,
            Pb, 512, nullptr);
        add_ln_kernel<<<M, 256, 0, stream>>>(X, Pb, ln2_g + l * 512, ln2_b + l * 512, Xb);
    }

    decoder_kernel<<<M / 4, 256, 0, stream>>>(X, dec_w, dec_b, outp);
}

// Round 11
// 538.796 us; speedup vs baseline: 1.0296x; 1.0296x over previous
//
#include <hip/hip_runtime.h>

#define S_LEN 2048
#define DMODEL 512

typedef __attribute__((ext_vector_type(8))) short bf16x8;
typedef __attribute__((ext_vector_type(4))) float f32x4;
typedef __attribute__((ext_vector_type(4))) unsigned short u16x4;
typedef __attribute__((ext_vector_type(8))) unsigned short u16x8;
typedef __attribute__((ext_vector_type(2))) unsigned int u32x2;

__device__ __forceinline__ unsigned short f2bf(float f) {
    unsigned int u = __float_as_uint(f);
    u += 0x7fff + ((u >> 16) & 1);            // RNE
    return (unsigned short)(u >> 16);
}
__device__ __forceinline__ float bf2f(unsigned short h) {
    return __uint_as_float(((unsigned int)h) << 16);
}
__device__ __forceinline__ void gll16(const void* g, void* l) {
    __builtin_amdgcn_global_load_lds(
        (const __attribute__((address_space(1))) unsigned int*)g,
        (__attribute__((address_space(3))) unsigned int*)l, 16, 0, 0);
}

// ---------------- fp32 -> bf16 bulk convert (all 4 weight tensors, 1 launch) ----------------
__global__ __launch_bounds__(256) void conv_all(
    const float4* __restrict__ in_w, const float4* __restrict__ out_w,
    const float4* __restrict__ ff1_w, const float4* __restrict__ ff2_w,
    u16x4* __restrict__ in_wb, u16x4* __restrict__ out_wb,
    u16x4* __restrict__ ff1_wb, u16x4* __restrict__ ff2_wb)
{
    int i = blockIdx.x * 256 + threadIdx.x;
    const float4* src; u16x4* dst; int j;
    if (i < 589824)        { src = in_w;  dst = in_wb;  j = i; }
    else if (i < 786432)   { src = out_w; dst = out_wb; j = i - 589824; }
    else if (i < 1572864)  { src = ff1_w; dst = ff1_wb; j = i - 786432; }
    else                   { src = ff2_w; dst = ff2_wb; j = i - 1572864; }
    float4 v = src[j];
    u16x4 o = { f2bf(v.x), f2bf(v.y), f2bf(v.z), f2bf(v.w) };
    dst[j] = o;
}

// ---------------- embedding + positional encoding ----------------
__global__ __launch_bounds__(256) void embed_kernel(
    const float* __restrict__ src, const float* __restrict__ ew,
    const float* __restrict__ eb, float* __restrict__ X,
    unsigned short* __restrict__ Xb)
{
    int rid = blockIdx.x;              // b*S + s
    int s = rid & (S_LEN - 1);
    int tid = threadIdx.x;
    __shared__ float sr[25];
    if (tid < 25) sr[tid] = src[rid * 25 + tid];
    __syncthreads();
    #pragma unroll
    for (int rep = 0; rep < 2; rep++) {
        int d = tid + rep * 256;
        float a = eb[d];
        #pragma unroll
        for (int k = 0; k < 25; k++) a = fmaf(sr[k], ew[d * 25 + k], a);
        int i2 = d & ~1;
        float div = expf(-(float)i2 * (9.210340371976184f / 512.f));
        float ang = (float)s * div;
        a += (d & 1) ? cosf(ang) : sinf(ang);
        X[(size_t)rid * DMODEL + d] = a;
        Xb[(size_t)rid * DMODEL + d] = f2bf(a);
    }
}

// ---------------- bf16 MFMA GEMM: C = A @ W^T + bias ----------------
// Double-buffered LDS pipeline: stage(kk+1) issued BEFORE computing tile kk.
template<int MODE, int BN>
__global__ __launch_bounds__(256) void gemm_bf16(
    const unsigned short* __restrict__ A, int lda,
    const unsigned short* __restrict__ W, int K,
    const float* __restrict__ bias,
    unsigned short* __restrict__ out, int ldc,
    unsigned short* __restrict__ out2)
{
    constexpr int NJ = BN / 32;
    __shared__ __align__(16) unsigned short As[2][128 * 64];
    __shared__ __align__(16) unsigned short Ws[2][BN * 64];
    int tid = threadIdx.x;
    int lane = tid & 63, w = tid >> 6;
    int g = lane >> 4, c15 = lane & 15;
    int wm = w >> 1, wn = w & 1;
    int bm, bn;
    if (BN == 64) {
        int raw = blockIdx.x;
        int lid = ((raw & 7) << 6) | (raw >> 3);  // consecutive lid -> same XCD
        bn = lid & 7; bm = lid >> 3;
    } else {
        bm = blockIdx.y; bn = blockIdx.x;
    }

    f32x4 acc[4][NJ];
    #pragma unroll
    for (int i = 0; i < 4; i++)
        #pragma unroll
        for (int j = 0; j < NJ; j++) acc[i][j] = (f32x4){0.f, 0.f, 0.f, 0.f};

    auto stage = [&](int kk, int bi) {
        #pragma unroll
        for (int i = 0; i < 4; i++) {
            int chunk = tid + i * 256;
            int r = chunk >> 3, c = chunk & 7;
            int cs = c ^ (r & 7);
            gll16(A + (size_t)(bm * 128 + r) * lda + kk * 64 + cs * 8,
                  (void*)(As[bi] + chunk * 8));
        }
        #pragma unroll
        for (int i = 0; i < BN / 32; i++) {
            int chunk = tid + i * 256;
            int r = chunk >> 3, c = chunk & 7;
            int cs = c ^ (r & 7);
            gll16(W + (size_t)(bn * BN + r) * K + kk * 64 + cs * 8,
                  (void*)(Ws[bi] + chunk * 8));
        }
    };

    const int nk = K >> 6;
    stage(0, 0);
    __syncthreads();          // drain prologue staging
    int buf = 0;

    for (int kk = 0; kk < nk; kk++) {
        if (kk + 1 < nk) stage(kk + 1, buf ^ 1);   // prefetch overlaps compute
        bf16x8 a[4][2], b[NJ][2];
        #pragma unroll
        for (int mi = 0; mi < 4; mi++) {
            int row = wm * 64 + mi * 16 + c15;
            #pragma unroll
            for (int h = 0; h < 2; h++) {
                int ck = (h * 4 + g) ^ (row & 7);
                a[mi][h] = *(const bf16x8*)((const char*)As[buf] + row * 128 + ck * 16);
            }
        }
        #pragma unroll
        for (int nj = 0; nj < NJ; nj++) {
            int row = wn * (BN / 2) + nj * 16 + c15;
            #pragma unroll
            for (int h = 0; h < 2; h++) {
                int ck = (h * 4 + g) ^ (row & 7);
                b[nj][h] = *(const bf16x8*)((const char*)Ws[buf] + row * 128 + ck * 16);
            }
        }
        __builtin_amdgcn_s_setprio(1);
        #pragma unroll
        for (int h = 0; h < 2; h++)
            #pragma unroll
            for (int mi = 0; mi < 4; mi++)
                #pragma unroll
                for (int nj = 0; nj < NJ; nj++)
                    acc[mi][nj] = __builtin_amdgcn_mfma_f32_16x16x32_bf16(
                        a[mi][h], b[nj][h], acc[mi][nj], 0, 0, 0);
        __builtin_amdgcn_s_setprio(0);
        __syncthreads();      // drains prefetch vmcnt + buffer handoff
        buf ^= 1;
    }
    #pragma unroll
    for (int nj = 0; nj < NJ; nj++) {
        int colb = bn * BN + wn * (BN / 2) + nj * 16;
        float bv = bias[colb + c15];
        #pragma unroll
        for (int mi = 0; mi < 4; mi++) {
            int rowb = bm * 128 + wm * 64 + mi * 16 + g * 4;
            if (MODE == 3 && colb >= 1024) {     // V -> transposed global
                int cv = colb - 1024 + c15;
                int hh = cv >> 7, d = cv & 127;
                int bb = rowb >> 11, t = rowb & (S_LEN - 1);
                u16x4 pk;
                #pragma unroll
                for (int r = 0; r < 4; r++) pk[r] = f2bf(acc[mi][nj][r] + bv);
                *(u16x4*)(out2 + ((size_t)(bb * 4 + hh) * 128 + d) * S_LEN + t) = pk;
            } else {
                #pragma unroll
                for (int r = 0; r < 4; r++) {
                    float v = acc[mi][nj][r] + bv;
                    if (MODE == 2) v = fmaxf(v, 0.f);
                    out[(size_t)(rowb + r) * ldc + colb + c15] = f2bf(v);
                }
            }
        }
    }
}

// ---------------- bf16 MFMA flash attention (round-9 measured-best config) ----------------
// KVBLK=32, split-K for qb>=16, double-buffered global_load_lds staging.
__global__ __launch_bounds__(256) void flash_attn(
    const unsigned short* __restrict__ QKb,
    const unsigned short* __restrict__ Vt,
    unsigned short* __restrict__ Ob,
    unsigned short* __restrict__ Opart,   // [512][64*128] bf16
    float* __restrict__ Mpart,            // [512][64]
    float* __restrict__ Lpart)            // [512][64]
{
    __shared__ __align__(16) unsigned short Ks[2][32 * 128];
    __shared__ __align__(16) unsigned short Vts[2][128 * 32];
    __shared__ __align__(16) unsigned short Plds[4][16 * 40];   // stride 40 u16
    const float scale = 0.08838834764831845f;   // 1/sqrt(128)
    int tid = threadIdx.x;
    int lane = tid & 63, w = tid >> 6;
    int g = lane >> 4, c15 = lane & 15;
    int raw = blockIdx.x;
    int lid = (raw & 7) * 96 + (raw >> 3);       // XCD-chunked (768 = 8*96)
    int bh = lid / 48, idx = lid - bh * 48;
    int b = bh >> 2, h = bh & 3;
    // 32-token KV tiles: qb has 2qb+2 tiles total.
    int qb, kt0, nkt, split;
    if (idx < 16) { qb = idx; kt0 = 0; nkt = 2 * qb + 2; split = -1; }
    else {
        int s = idx - 16;
        qb = 16 + (s >> 1);
        int j = s & 1;
        kt0 = j * (qb + 1);
        nkt = qb + 1;
        split = bh * 32 + (qb - 16) * 2 + j;
    }

    // Q fragments (B-operand): this lane's q-row = qb*64 + w*16 + c15
    bf16x8 q[4];
    {
        const unsigned short* qrow =
            QKb + (size_t)(b * S_LEN + qb * 64 + w * 16 + c15) * 1024 + h * 128;
        #pragma unroll
        for (int k0 = 0; k0 < 4; k0++) q[k0] = *(const bf16x8*)(qrow + k0 * 32 + g * 8);
    }
    f32x4 o[8];
    #pragma unroll
    for (int cd = 0; cd < 8; cd++) o[cd] = (f32x4){0.f, 0.f, 0.f, 0.f};
    float m = -3e38f, l = 0.f;

    auto stage = [&](int kt, int bi) {
        #pragma unroll
        for (int i = 0; i < 2; i++) {      // K tile: 32 rows x 16 chunks (swizzled src)
            int chunk = tid + i * 256;
            int r = chunk >> 4, c = chunk & 15;
            int cs = (c & 8) | ((c ^ r) & 7);
            gll16(QKb + (size_t)(b * S_LEN + kt * 32 + r) * 1024 + 512 + h * 128 + cs * 8,
                  (void*)(Ks[bi] + chunk * 8));
        }
        #pragma unroll
        for (int i = 0; i < 2; i++) {      // Vt tile: 128 rows x 4 chunks
            int chunk = tid + i * 256;
            int r = chunk >> 2, c = chunk & 3;
            int cs = (c ^ r) & 3;
            gll16(Vt + ((size_t)(b * 4 + h) * 128 + r) * S_LEN + kt * 32 + cs * 8,
                  (void*)(Vts[bi] + chunk * 8));
        }
    };

    stage(kt0, 0);
    __syncthreads();          // drains vmcnt(0) + barrier
    int buf = 0;

    for (int t = 0; t < nkt; t++) {
        int kt = kt0 + t;
        if (t + 1 < nkt) stage(kt + 1, buf ^ 1);   // prefetch overlaps compute
        // --- S^T = K Q^T (swapped): lane holds q-row c15, tokens c*16+g*4+r ---
        f32x4 sf[2];
        __builtin_amdgcn_s_setprio(1);
        #pragma unroll
        for (int c = 0; c < 2; c++) {
            sf[c] = (f32x4){0.f, 0.f, 0.f, 0.f};
            int tok16 = c * 16 + c15;
            #pragma unroll
            for (int k0 = 0; k0 < 4; k0++) {
                int ck = k0 * 4 + g;
                int cs = (ck & 8) | ((ck ^ tok16) & 7);
                bf16x8 kf = *(const bf16x8*)((const char*)Ks[buf] + tok16 * 256 + cs * 16);
                sf[c] = __builtin_amdgcn_mfma_f32_16x16x32_bf16(kf, q[k0], sf[c], 0, 0, 0);
            }
        }
        __builtin_amdgcn_s_setprio(0);
        // --- mask: last two tiles only (incl. PRE block) ---
        if (kt >= 2 * qb) {
            int qr = qb * 64 + w * 16 + c15;
            #pragma unroll
            for (int c = 0; c < 2; c++)
                #pragma unroll
                for (int r = 0; r < 4; r++) {
                    int tok = kt * 32 + c * 16 + g * 4 + r;
                    bool ok = (tok <= qr) || (qr < 20 && tok < 20);
                    if (!ok) sf[c][r] = -3e38f;
                }
        }
        // --- row max: in-lane tree + 2 shfl ---
        float t0 = fmaxf(fmaxf(sf[0][0], sf[0][1]), fmaxf(sf[0][2], sf[0][3]));
        float t1 = fmaxf(fmaxf(sf[1][0], sf[1][1]), fmaxf(sf[1][2], sf[1][3]));
        float mt = fmaxf(t0, t1);
        mt = fmaxf(mt, __shfl_xor(mt, 16));
        mt = fmaxf(mt, __shfl_xor(mt, 32));
        // --- defer-max (T13): 8 nats = 90.5 raw ---
        bool need = !__all(mt <= m + 90.5f);
        float sc = 1.f;
        if (need) {
            float mn = fmaxf(m, mt);
            sc = __expf((m - mn) * scale);
            m = mn;
        }
        float msc = m * scale;
        #pragma unroll
        for (int c = 0; c < 2; c++)
            #pragma unroll
            for (int r = 0; r < 4; r++)
                sf[c][r] = __expf(fmaf(sf[c][r], scale, -msc));
        float s0 = (sf[0][0] + sf[0][1]) + (sf[0][2] + sf[0][3]);
        float s1 = (sf[1][0] + sf[1][1]) + (sf[1][2] + sf[1][3]);
        float ls = s0 + s1;
        ls += __shfl_xor(ls, 16);
        ls += __shfl_xor(ls, 32);
        if (need) l *= sc;
        l += ls;
        // --- P -> Plds[q-row][token], packed b64 writes ---
        #pragma unroll
        for (int c = 0; c < 2; c++) {
            unsigned int lo = ((unsigned int)f2bf(sf[c][1]) << 16) | f2bf(sf[c][0]);
            unsigned int hi = ((unsigned int)f2bf(sf[c][3]) << 16) | f2bf(sf[c][2]);
            u32x2 pk = {lo, hi};
            *(u32x2*)&Plds[w][c15 * 40 + c * 16 + g * 4] = pk;
        }
        // --- rescale O (skipped when deferred) ---
        if (need) {
            float r0 = __shfl(sc, g * 4 + 0);
            float r1 = __shfl(sc, g * 4 + 1);
            float r2 = __shfl(sc, g * 4 + 2);
            float r3 = __shfl(sc, g * 4 + 3);
            #pragma unroll
            for (int cd = 0; cd < 8; cd++) {
                o[cd][0] *= r0; o[cd][1] *= r1; o[cd][2] *= r2; o[cd][3] *= r3;
            }
        }
        // --- O += P V (single K=32 MFMA per d-group) ---
        bf16x8 pa = *(const bf16x8*)((const char*)&Plds[w][0] + c15 * 80 + g * 16);
        __builtin_amdgcn_s_setprio(1);
        #pragma unroll
        for (int cd = 0; cd < 8; cd++) {
            int dv = cd * 16 + c15;
            int cs = (g ^ dv) & 3;
            bf16x8 vf = *(const bf16x8*)((const char*)Vts[buf] + dv * 64 + cs * 16);
            o[cd] = __builtin_amdgcn_mfma_f32_16x16x32_bf16(pa, vf, o[cd], 0, 0, 0);
        }
        __builtin_amdgcn_s_setprio(0);
        __syncthreads();      // drains prefetch vmcnt + buffer handoff
        buf ^= 1;
    }

    if (split < 0) {
        float li0 = 1.f / __shfl(l, g * 4 + 0);
        float li1 = 1.f / __shfl(l, g * 4 + 1);
        float li2 = 1.f / __shfl(l, g * 4 + 2);
        float li3 = 1.f / __shfl(l, g * 4 + 3);
        size_t obase = (size_t)(b * S_LEN + qb * 64 + w * 16 + g * 4) * 512 + h * 128;
        #pragma unroll
        for (int cd = 0; cd < 8; cd++) {
            Ob[obase + 0 * 512 + cd * 16 + c15] = f2bf(o[cd][0] * li0);
            Ob[obase + 1 * 512 + cd * 16 + c15] = f2bf(o[cd][1] * li1);
            Ob[obase + 2 * 512 + cd * 16 + c15] = f2bf(o[cd][2] * li2);
            Ob[obase + 3 * 512 + cd * 16 + c15] = f2bf(o[cd][3] * li3);
        }
    } else {
        unsigned short* op = Opart + (size_t)split * 8192;
        int rb = w * 16 + g * 4;
        #pragma unroll
        for (int cd = 0; cd < 8; cd++) {
            op[(rb + 0) * 128 + cd * 16 + c15] = f2bf(o[cd][0]);
            op[(rb + 1) * 128 + cd * 16 + c15] = f2bf(o[cd][1]);
            op[(rb + 2) * 128 + cd * 16 + c15] = f2bf(o[cd][2]);
            op[(rb + 3) * 128 + cd * 16 + c15] = f2bf(o[cd][3]);
        }
        if (g == 0) {
            Mpart[split * 64 + w * 16 + c15] = m;
            Lpart[split * 64 + w * 16 + c15] = l;
        }
    }
}

// ---------------- merge split-K partials (qb 16..31) ----------------
__global__ __launch_bounds__(256) void attn_merge(
    const unsigned short* __restrict__ Opart,
    const float* __restrict__ Mpart, const float* __restrict__ Lpart,
    unsigned short* __restrict__ Ob)
{
    const float scale = 0.08838834764831845f;
    int bid = blockIdx.x;                 // bh*16 + (qb-16)
    int bh = bid >> 4, qe = bid & 15;
    int qb = 16 + qe;
    int b = bh >> 2, h = bh & 3;
    int p0 = bh * 32 + qe * 2;
    int t = threadIdx.x;
    int r = t >> 2, dq = t & 3;
    float m0 = Mpart[p0 * 64 + r], m1 = Mpart[(p0 + 1) * 64 + r];
    float l0 = Lpart[p0 * 64 + r], l1 = Lpart[(p0 + 1) * 64 + r];
    float ms = fmaxf(m0, m1);
    float w0 = __expf((m0 - ms) * scale), w1 = __expf((m1 - ms) * scale);
    float linv = 1.f / (l0 * w0 + l1 * w1);
    w0 *= linv; w1 *= linv;
    const unsigned short* o0 = Opart + (size_t)p0 * 8192 + r * 128 + dq * 32;
    const unsigned short* o1 = o0 + 8192;
    unsigned short* od = Ob + (size_t)(b * S_LEN + qb * 64 + r) * 512 + h * 128 + dq * 32;
    #pragma unroll
    for (int i = 0; i < 4; i++) {
        u16x8 a = *(const u16x8*)(o0 + i * 8);
        u16x8 c = *(const u16x8*)(o1 + i * 8);
        u16x8 d;
        #pragma unroll
        for (int j = 0; j < 8; j++)
            d[j] = f2bf(bf2f(a[j]) * w0 + bf2f(c[j]) * w1);
        *(u16x8*)(od + i * 8) = d;
    }
}

// ---------------- X = LayerNorm(X + D)*g + b ;  Xb = bf16(X) ----------------
// Wave-per-row: 4 rows/block, vectorized 16B loads, pure shfl reduce,
// no LDS, no barrier.
__global__ __launch_bounds__(256) void add_ln_kernel(
    float* __restrict__ X, const unsigned short* __restrict__ D,
    const float* __restrict__ gw, const float* __restrict__ bw,
    unsigned short* __restrict__ Xb)
{
    int wv = threadIdx.x >> 6, lane = threadIdx.x & 63;
    int row = blockIdx.x * 4 + wv;
    size_t base = (size_t)row * DMODEL + lane * 8;
    float4 x0 = *(const float4*)(X + base);
    float4 x1 = *(const float4*)(X + base + 4);
    u16x8 d8 = *(const u16x8*)(D + base);
    float v[8];
    v[0] = x0.x + bf2f(d8[0]); v[1] = x0.y + bf2f(d8[1]);
    v[2] = x0.z + bf2f(d8[2]); v[3] = x0.w + bf2f(d8[3]);
    v[4] = x1.x + bf2f(d8[4]); v[5] = x1.y + bf2f(d8[5]);
    v[6] = x1.z + bf2f(d8[6]); v[7] = x1.w + bf2f(d8[7]);
    float s = 0.f, sq = 0.f;
    #pragma unroll
    for (int i = 0; i < 8; i++) { s += v[i]; sq = fmaf(v[i], v[i], sq); }
    #pragma unroll
    for (int off = 32; off > 0; off >>= 1) {
        s  += __shfl_xor(s, off);
        sq += __shfl_xor(sq, off);
    }
    float mu = s * (1.f / DMODEL);
    float var = sq * (1.f / DMODEL) - mu * mu;
    float rs = rsqrtf(var + 1e-5f);
    float4 g0 = *(const float4*)(gw + lane * 8);
    float4 g1 = *(const float4*)(gw + lane * 8 + 4);
    float4 b0 = *(const float4*)(bw + lane * 8);
    float4 b1 = *(const float4*)(bw + lane * 8 + 4);
    float y[8];
    y[0] = (v[0] - mu) * rs * g0.x + b0.x; y[1] = (v[1] - mu) * rs * g0.y + b0.y;
    y[2] = (v[2] - mu) * rs * g0.z + b0.z; y[3] = (v[3] - mu) * rs * g0.w + b0.w;
    y[4] = (v[4] - mu) * rs * g1.x + b1.x; y[5] = (v[5] - mu) * rs * g1.y + b1.y;
    y[6] = (v[6] - mu) * rs * g1.z + b1.z; y[7] = (v[7] - mu) * rs * g1.w + b1.w;
    float4 o0 = { y[0], y[1], y[2], y[3] };
    float4 o1 = { y[4], y[5], y[6], y[7] };
    *(float4*)(X + base) = o0;
    *(float4*)(X + base + 4) = o1;
    u16x8 ob;
    #pragma unroll
    for (int i = 0; i < 8; i++) ob[i] = f2bf(y[i]);
    *(u16x8*)(Xb + base) = ob;
}

// ---------------- out = tanh(X @ dec_w^T + dec_b) * 10 ----------------
__global__ __launch_bounds__(256) void decoder_kernel(
    const float* __restrict__ X, const float* __restrict__ w,
    const float* __restrict__ bias, float* __restrict__ out)
{
    int tid = threadIdx.x;
    int lane = tid & 63;
    int row = blockIdx.x * 4 + (tid >> 6);
    float s = 0.f;
    size_t base = (size_t)row * DMODEL;
    #pragma unroll
    for (int i = 0; i < 8; i++) s = fmaf(X[base + lane + i * 64], w[lane + i * 64], s);
    #pragma unroll
    for (int off = 32; off > 0; off >>= 1) s += __shfl_down(s, off);
    if (lane == 0) out[row] = tanhf(s + bias[0]) * 10.0f;
}

extern "C" void kernel_launch(void* const* d_in, const int* in_sizes, int n_in,
                              void* d_out, int out_size, void* d_ws, size_t ws_size,
                              hipStream_t stream)
{
    const float* src   = (const float*)d_in[0];
    const float* emb_w = (const float*)d_in[1];
    const float* emb_b = (const float*)d_in[2];
    const float* in_w  = (const float*)d_in[3];
    const float* in_b  = (const float*)d_in[4];
    const float* out_w = (const float*)d_in[5];
    const float* out_b = (const float*)d_in[6];
    const float* ln1_g = (const float*)d_in[7];
    const float* ln1_b = (const float*)d_in[8];
    const float* ln2_g = (const float*)d_in[9];
    const float* ln2_b = (const float*)d_in[10];
    const float* ff1_w = (const float*)d_in[11];
    const float* ff1_b = (const float*)d_in[12];
    const float* ff2_w = (const float*)d_in[13];
    const float* ff2_b = (const float*)d_in[14];
    const float* dec_w = (const float*)d_in[15];
    const float* dec_b = (const float*)d_in[16];

    char* ws = (char*)d_ws;
    float*          X   = (float*)ws;                              // 16 MB
    unsigned short* Xb  = (unsigned short*)(ws + (16u << 20));     //  8 MB
    unsigned short* Pb  = (unsigned short*)(ws + (24u << 20));     //  8 MB
    unsigned short* Ob  = (unsigned short*)(ws + (32u << 20));     //  8 MB
    unsigned short* QKb = (unsigned short*)(ws + (40u << 20));     // 16 MB
    unsigned short* Vt  = (unsigned short*)(ws + (56u << 20));     //  8 MB
    unsigned short* Hb  = (unsigned short*)(ws + (40u << 20));     // 32 MB (overlaps QKb+Vt)
    // Attention split-K partials overlay regions that are DEAD during
    // flash+merge: Opart over Xb (rewritten by add_ln before next read),
    // Mpart/Lpart over Pb (written by O-proj after merge).
    unsigned short* Opart = (unsigned short*)(ws + (16u << 20));   // 512*8192 bf16 = 8 MB
    float* Mpart = (float*)(ws + (24u << 20));                     // 512*64 f32
    float* Lpart = Mpart + 512 * 64;
    unsigned short* in_wb  = (unsigned short*)(ws + (72u << 20));
    unsigned short* out_wb = in_wb  + 3u * 1536 * 512;
    unsigned short* ff1_wb = out_wb + 3u * 512 * 512;
    unsigned short* ff2_wb = ff1_wb + 3u * 2048 * 512;
    float* outp = (float*)d_out;
    const int M = 4 * S_LEN;   // 8192

    conv_all<<<9216, 256, 0, stream>>>(
        (const float4*)in_w, (const float4*)out_w,
        (const float4*)ff1_w, (const float4*)ff2_w,
        (u16x4*)in_wb, (u16x4*)out_wb, (u16x4*)ff1_wb, (u16x4*)ff2_wb);

    embed_kernel<<<M, 256, 0, stream>>>(src, emb_w, emb_b, X, Xb);

    for (int l = 0; l < 3; l++) {
        gemm_bf16<3, 128><<<dim3(12, 64), 256, 0, stream>>>(
            Xb, 512, in_wb + (size_t)l * 1536 * 512, 512, in_b + l * 1536,
            QKb, 1024, Vt);
        flash_attn<<<768, 256, 0, stream>>>(QKb, Vt, Ob, Opart, Mpart, Lpart);
        attn_merge<<<256, 256, 0, stream>>>(Opart, Mpart, Lpart, Ob);
        gemm_bf16<1, 64><<<dim3(512), 256, 0, stream>>>(
            Ob, 512, out_wb + (size_t)l * 512 * 512, 512, out_b + l * 512,
            Pb, 512, nullptr);
        add_ln_kernel<<<M / 4, 256, 0, stream>>>(X, Pb, ln1_g + l * 512, ln1_b + l * 512, Xb);
        gemm_bf16<2, 128><<<dim3(16, 64), 256, 0, stream>>>(
            Xb, 512, ff1_wb + (size_t)l * 2048 * 512, 512, ff1_b + l * 2048,
            Hb, 2048, nullptr);
        gemm_bf16<1, 64><<<dim3(512), 256, 0, stream>>>(
            Hb, 2048, ff2_wb + (size_t)l * 512 * 2048, 2048, ff2_b + l * 512,
            Pb, 512, nullptr);
        add_ln_kernel<<<M / 4, 256, 0, stream>>>(X, Pb, ln2_g + l * 512, ln2_b + l * 512, Xb);
    }

    decoder_kernel<<<M / 4, 256, 0, stream>>>(X, dec_w, dec_b, outp);
}

// Round 12
// 517.038 us; speedup vs baseline: 1.0729x; 1.0421x over previous
//
#include <hip/hip_runtime.h>

#define S_LEN 2048
#define DMODEL 512

typedef __attribute__((ext_vector_type(8))) short bf16x8;
typedef __attribute__((ext_vector_type(4))) float f32x4;
typedef __attribute__((ext_vector_type(4))) unsigned short u16x4;
typedef __attribute__((ext_vector_type(8))) unsigned short u16x8;
typedef __attribute__((ext_vector_type(2))) unsigned int u32x2;

__device__ __forceinline__ unsigned short f2bf(float f) {
    unsigned int u = __float_as_uint(f);
    u += 0x7fff + ((u >> 16) & 1);            // RNE
    return (unsigned short)(u >> 16);
}
__device__ __forceinline__ float bf2f(unsigned short h) {
    return __uint_as_float(((unsigned int)h) << 16);
}
__device__ __forceinline__ void gll16(const void* g, void* l) {
    __builtin_amdgcn_global_load_lds(
        (const __attribute__((address_space(1))) unsigned int*)g,
        (__attribute__((address_space(3))) unsigned int*)l, 16, 0, 0);
}

// ---------------- fp32 -> bf16 bulk convert (all 4 weight tensors, 1 launch) ----------------
__global__ __launch_bounds__(256) void conv_all(
    const float4* __restrict__ in_w, const float4* __restrict__ out_w,
    const float4* __restrict__ ff1_w, const float4* __restrict__ ff2_w,
    u16x4* __restrict__ in_wb, u16x4* __restrict__ out_wb,
    u16x4* __restrict__ ff1_wb, u16x4* __restrict__ ff2_wb)
{
    int i = blockIdx.x * 256 + threadIdx.x;
    const float4* src; u16x4* dst; int j;
    if (i < 589824)        { src = in_w;  dst = in_wb;  j = i; }
    else if (i < 786432)   { src = out_w; dst = out_wb; j = i - 589824; }
    else if (i < 1572864)  { src = ff1_w; dst = ff1_wb; j = i - 786432; }
    else                   { src = ff2_w; dst = ff2_wb; j = i - 1572864; }
    float4 v = src[j];
    u16x4 o = { f2bf(v.x), f2bf(v.y), f2bf(v.z), f2bf(v.w) };
    dst[j] = o;
}

// ---------------- embedding + positional encoding ----------------
__global__ __launch_bounds__(256) void embed_kernel(
    const float* __restrict__ src, const float* __restrict__ ew,
    const float* __restrict__ eb, float* __restrict__ X,
    unsigned short* __restrict__ Xb)
{
    int rid = blockIdx.x;              // b*S + s
    int s = rid & (S_LEN - 1);
    int tid = threadIdx.x;
    __shared__ float sr[25];
    if (tid < 25) sr[tid] = src[rid * 25 + tid];
    __syncthreads();
    #pragma unroll
    for (int rep = 0; rep < 2; rep++) {
        int d = tid + rep * 256;
        float a = eb[d];
        #pragma unroll
        for (int k = 0; k < 25; k++) a = fmaf(sr[k], ew[d * 25 + k], a);
        int i2 = d & ~1;
        float div = expf(-(float)i2 * (9.210340371976184f / 512.f));
        float ang = (float)s * div;
        a += (d & 1) ? cosf(ang) : sinf(ang);
        X[(size_t)rid * DMODEL + d] = a;
        Xb[(size_t)rid * DMODEL + d] = f2bf(a);
    }
}

// ---------------- bf16 MFMA GEMM: C = A @ W^T + bias ----------------
// Double-buffered LDS pipeline + XCD-chunked 1D grid + per-wave
// LDS-transpose epilogue (vectorized coalesced stores; MODE3 V-transpose
// comes out coalesced along t).
template<int MODE, int BN>
__global__ __launch_bounds__(256) void gemm_bf16(
    const unsigned short* __restrict__ A, int lda,
    const unsigned short* __restrict__ W, int K,
    const float* __restrict__ bias,
    unsigned short* __restrict__ out, int ldc,
    unsigned short* __restrict__ out2, int nbn)
{
    constexpr int NJ = BN / 32;
    constexpr int WC = BN / 2;                 // wave output cols
    __shared__ __align__(16) unsigned short LdsBuf[2][(128 + BN) * 64];
    int tid = threadIdx.x;
    int lane = tid & 63, w = tid >> 6;
    int g = lane >> 4, c15 = lane & 15;
    int wm = w >> 1, wn = w & 1;
    int bm, bn;
    if (BN == 64) {
        int raw = blockIdx.x;
        int lid = ((raw & 7) << 6) | (raw >> 3);  // consecutive lid -> same XCD
        bn = lid & 7; bm = lid >> 3;
    } else {
        int raw = blockIdx.x;
        int per = gridDim.x >> 3;                 // blocks per XCD chunk
        int lid = (raw & 7) * per + (raw >> 3);   // consecutive lid -> same XCD
        bn = lid % nbn; bm = lid / nbn;           // bn fastest: share A panel
    }

    f32x4 acc[4][NJ];
    #pragma unroll
    for (int i = 0; i < 4; i++)
        #pragma unroll
        for (int j = 0; j < NJ; j++) acc[i][j] = (f32x4){0.f, 0.f, 0.f, 0.f};

    auto stage = [&](int kk, int bi) {
        #pragma unroll
        for (int i = 0; i < 4; i++) {
            int chunk = tid + i * 256;
            int r = chunk >> 3, c = chunk & 7;
            int cs = c ^ (r & 7);
            gll16(A + (size_t)(bm * 128 + r) * lda + kk * 64 + cs * 8,
                  (void*)(LdsBuf[bi] + chunk * 8));
        }
        #pragma unroll
        for (int i = 0; i < BN / 32; i++) {
            int chunk = tid + i * 256;
            int r = chunk >> 3, c = chunk & 7;
            int cs = c ^ (r & 7);
            gll16(W + (size_t)(bn * BN + r) * K + kk * 64 + cs * 8,
                  (void*)(LdsBuf[bi] + 128 * 64 + chunk * 8));
        }
    };

    const int nk = K >> 6;
    stage(0, 0);
    __syncthreads();          // drain prologue staging
    int buf = 0;

    for (int kk = 0; kk < nk; kk++) {
        if (kk + 1 < nk) stage(kk + 1, buf ^ 1);   // prefetch overlaps compute
        bf16x8 a[4][2], b[NJ][2];
        #pragma unroll
        for (int mi = 0; mi < 4; mi++) {
            int row = wm * 64 + mi * 16 + c15;
            #pragma unroll
            for (int h = 0; h < 2; h++) {
                int ck = (h * 4 + g) ^ (row & 7);
                a[mi][h] = *(const bf16x8*)((const char*)LdsBuf[buf] + row * 128 + ck * 16);
            }
        }
        #pragma unroll
        for (int nj = 0; nj < NJ; nj++) {
            int row = wn * WC + nj * 16 + c15;
            #pragma unroll
            for (int h = 0; h < 2; h++) {
                int ck = (h * 4 + g) ^ (row & 7);
                b[nj][h] = *(const bf16x8*)((const char*)(LdsBuf[buf] + 128 * 64)
                                            + row * 128 + ck * 16);
            }
        }
        __builtin_amdgcn_s_setprio(1);
        #pragma unroll
        for (int h = 0; h < 2; h++)
            #pragma unroll
            for (int mi = 0; mi < 4; mi++)
                #pragma unroll
                for (int nj = 0; nj < NJ; nj++)
                    acc[mi][nj] = __builtin_amdgcn_mfma_f32_16x16x32_bf16(
                        a[mi][h], b[nj][h], acc[mi][nj], 0, 0, 0);
        __builtin_amdgcn_s_setprio(0);
        __syncthreads();      // drains prefetch vmcnt + buffer handoff
        buf ^= 1;
    }

    // ---- per-wave LDS-transpose epilogue (staging LDS is dead past here) ----
    unsigned short* scr = (unsigned short*)LdsBuf + (size_t)w * 4608;  // [64][72]
    int colb0 = bn * BN + wn * WC;
    int rowb0 = bm * 128 + wm * 64;
    bool vout = (MODE == 3) && (colb0 >= 1024);
    #pragma unroll
    for (int nj = 0; nj < NJ; nj++) {
        float bv = bias[colb0 + nj * 16 + c15];
        #pragma unroll
        for (int mi = 0; mi < 4; mi++) {
            #pragma unroll
            for (int r = 0; r < 4; r++) {
                float v = acc[mi][nj][r] + bv;
                if (MODE == 2) v = fmaxf(v, 0.f);
                int rl = mi * 16 + g * 4 + r;
                int cl = nj * 16 + c15;
                if (!vout) scr[rl * 72 + cl] = f2bf(v);
                else       scr[cl * 72 + rl] = f2bf(v);   // transposed for V
            }
        }
    }
    // per-wave scratch: no barrier needed (compiler waits lgkmcnt on reads)
    constexpr int NP = WC / 8;        // 8 passes (BN=128) or 4 (BN=64)
    if (!vout) {
        #pragma unroll
        for (int p = 0; p < NP; p++) {
            int idx = p * 64 + lane;
            int row = idx / (WC / 8);
            int cc  = (idx % (WC / 8)) * 8;
            u16x8 v = *(const u16x8*)(scr + row * 72 + cc);
            *(u16x8*)(out + (size_t)(rowb0 + row) * ldc + colb0 + cc) = v;
        }
    } else {
        int cv0 = colb0 - 1024;                   // multiple of 64
        int hh = cv0 >> 7, d0 = cv0 & 127;
        int bb = rowb0 >> 11, t0 = rowb0 & (S_LEN - 1);
        unsigned short* vbase = out2 + ((size_t)(bb * 4 + hh) * 128 + d0) * S_LEN + t0;
        #pragma unroll
        for (int p = 0; p < 8; p++) {
            int idx = p * 64 + lane;
            int rd = idx >> 3;                    // d offset 0..63
            int tc = (idx & 7) * 8;               // t offset
            u16x8 v = *(const u16x8*)(scr + rd * 72 + tc);
            *(u16x8*)(vbase + (size_t)rd * S_LEN + tc) = v;
        }
    }
}

// ---------------- bf16 MFMA flash attention (round-9 measured-best config) ----------------
// KVBLK=32, split-K for qb>=16, double-buffered global_load_lds staging.
__global__ __launch_bounds__(256) void flash_attn(
    const unsigned short* __restrict__ QKb,
    const unsigned short* __restrict__ Vt,
    unsigned short* __restrict__ Ob,
    unsigned short* __restrict__ Opart,   // [512][64*128] bf16
    float* __restrict__ Mpart,            // [512][64]
    float* __restrict__ Lpart)            // [512][64]
{
    __shared__ __align__(16) unsigned short Ks[2][32 * 128];
    __shared__ __align__(16) unsigned short Vts[2][128 * 32];
    __shared__ __align__(16) unsigned short Plds[4][16 * 40];   // stride 40 u16
    const float scale = 0.08838834764831845f;   // 1/sqrt(128)
    int tid = threadIdx.x;
    int lane = tid & 63, w = tid >> 6;
    int g = lane >> 4, c15 = lane & 15;
    int raw = blockIdx.x;
    int lid = (raw & 7) * 96 + (raw >> 3);       // XCD-chunked (768 = 8*96)
    int bh = lid / 48, idx = lid - bh * 48;
    int b = bh >> 2, h = bh & 3;
    // 32-token KV tiles: qb has 2qb+2 tiles total.
    int qb, kt0, nkt, split;
    if (idx < 16) { qb = idx; kt0 = 0; nkt = 2 * qb + 2; split = -1; }
    else {
        int s = idx - 16;
        qb = 16 + (s >> 1);
        int j = s & 1;
        kt0 = j * (qb + 1);
        nkt = qb + 1;
        split = bh * 32 + (qb - 16) * 2 + j;
    }

    // Q fragments (B-operand): this lane's q-row = qb*64 + w*16 + c15
    bf16x8 q[4];
    {
        const unsigned short* qrow =
            QKb + (size_t)(b * S_LEN + qb * 64 + w * 16 + c15) * 1024 + h * 128;
        #pragma unroll
        for (int k0 = 0; k0 < 4; k0++) q[k0] = *(const bf16x8*)(qrow + k0 * 32 + g * 8);
    }
    f32x4 o[8];
    #pragma unroll
    for (int cd = 0; cd < 8; cd++) o[cd] = (f32x4){0.f, 0.f, 0.f, 0.f};
    float m = -3e38f, l = 0.f;

    auto stage = [&](int kt, int bi) {
        #pragma unroll
        for (int i = 0; i < 2; i++) {      // K tile: 32 rows x 16 chunks (swizzled src)
            int chunk = tid + i * 256;
            int r = chunk >> 4, c = chunk & 15;
            int cs = (c & 8) | ((c ^ r) & 7);
            gll16(QKb + (size_t)(b * S_LEN + kt * 32 + r) * 1024 + 512 + h * 128 + cs * 8,
                  (void*)(Ks[bi] + chunk * 8));
        }
        #pragma unroll
        for (int i = 0; i < 2; i++) {      // Vt tile: 128 rows x 4 chunks
            int chunk = tid + i * 256;
            int r = chunk >> 2, c = chunk & 3;
            int cs = (c ^ r) & 3;
            gll16(Vt + ((size_t)(b * 4 + h) * 128 + r) * S_LEN + kt * 32 + cs * 8,
                  (void*)(Vts[bi] + chunk * 8));
        }
    };

    stage(kt0, 0);
    __syncthreads();          // drains vmcnt(0) + barrier
    int buf = 0;

    for (int t = 0; t < nkt; t++) {
        int kt = kt0 + t;
        if (t + 1 < nkt) stage(kt + 1, buf ^ 1);   // prefetch overlaps compute
        // --- S^T = K Q^T (swapped): lane holds q-row c15, tokens c*16+g*4+r ---
        f32x4 sf[2];
        __builtin_amdgcn_s_setprio(1);
        #pragma unroll
        for (int c = 0; c < 2; c++) {
            sf[c] = (f32x4){0.f, 0.f, 0.f, 0.f};
            int tok16 = c * 16 + c15;
            #pragma unroll
            for (int k0 = 0; k0 < 4; k0++) {
                int ck = k0 * 4 + g;
                int cs = (ck & 8) | ((ck ^ tok16) & 7);
                bf16x8 kf = *(const bf16x8*)((const char*)Ks[buf] + tok16 * 256 + cs * 16);
                sf[c] = __builtin_amdgcn_mfma_f32_16x16x32_bf16(kf, q[k0], sf[c], 0, 0, 0);
            }
        }
        __builtin_amdgcn_s_setprio(0);
        // --- mask: last two tiles only (incl. PRE block) ---
        if (kt >= 2 * qb) {
            int qr = qb * 64 + w * 16 + c15;
            #pragma unroll
            for (int c = 0; c < 2; c++)
                #pragma unroll
                for (int r = 0; r < 4; r++) {
                    int tok = kt * 32 + c * 16 + g * 4 + r;
                    bool ok = (tok <= qr) || (qr < 20 && tok < 20);
                    if (!ok) sf[c][r] = -3e38f;
                }
        }
        // --- row max: in-lane tree + 2 shfl ---
        float t0 = fmaxf(fmaxf(sf[0][0], sf[0][1]), fmaxf(sf[0][2], sf[0][3]));
        float t1 = fmaxf(fmaxf(sf[1][0], sf[1][1]), fmaxf(sf[1][2], sf[1][3]));
        float mt = fmaxf(t0, t1);
        mt = fmaxf(mt, __shfl_xor(mt, 16));
        mt = fmaxf(mt, __shfl_xor(mt, 32));
        // --- defer-max (T13): 8 nats = 90.5 raw ---
        bool need = !__all(mt <= m + 90.5f);
        float sc = 1.f;
        if (need) {
            float mn = fmaxf(m, mt);
            sc = __expf((m - mn) * scale);
            m = mn;
        }
        float msc = m * scale;
        #pragma unroll
        for (int c = 0; c < 2; c++)
            #pragma unroll
            for (int r = 0; r < 4; r++)
                sf[c][r] = __expf(fmaf(sf[c][r], scale, -msc));
        float s0 = (sf[0][0] + sf[0][1]) + (sf[0][2] + sf[0][3]);
        float s1 = (sf[1][0] + sf[1][1]) + (sf[1][2] + sf[1][3]);
        float ls = s0 + s1;
        ls += __shfl_xor(ls, 16);
        ls += __shfl_xor(ls, 32);
        if (need) l *= sc;
        l += ls;
        // --- P -> Plds[q-row][token], packed b64 writes ---
        #pragma unroll
        for (int c = 0; c < 2; c++) {
            unsigned int lo = ((unsigned int)f2bf(sf[c][1]) << 16) | f2bf(sf[c][0]);
            unsigned int hi = ((unsigned int)f2bf(sf[c][3]) << 16) | f2bf(sf[c][2]);
            u32x2 pk = {lo, hi};
            *(u32x2*)&Plds[w][c15 * 40 + c * 16 + g * 4] = pk;
        }
        // --- rescale O (skipped when deferred) ---
        if (need) {
            float r0 = __shfl(sc, g * 4 + 0);
            float r1 = __shfl(sc, g * 4 + 1);
            float r2 = __shfl(sc, g * 4 + 2);
            float r3 = __shfl(sc, g * 4 + 3);
            #pragma unroll
            for (int cd = 0; cd < 8; cd++) {
                o[cd][0] *= r0; o[cd][1] *= r1; o[cd][2] *= r2; o[cd][3] *= r3;
            }
        }
        // --- O += P V (single K=32 MFMA per d-group) ---
        bf16x8 pa = *(const bf16x8*)((const char*)&Plds[w][0] + c15 * 80 + g * 16);
        __builtin_amdgcn_s_setprio(1);
        #pragma unroll
        for (int cd = 0; cd < 8; cd++) {
            int dv = cd * 16 + c15;
            int cs = (g ^ dv) & 3;
            bf16x8 vf = *(const bf16x8*)((const char*)Vts[buf] + dv * 64 + cs * 16);
            o[cd] = __builtin_amdgcn_mfma_f32_16x16x32_bf16(pa, vf, o[cd], 0, 0, 0);
        }
        __builtin_amdgcn_s_setprio(0);
        __syncthreads();      // drains prefetch vmcnt + buffer handoff
        buf ^= 1;
    }

    if (split < 0) {
        float li0 = 1.f / __shfl(l, g * 4 + 0);
        float li1 = 1.f / __shfl(l, g * 4 + 1);
        float li2 = 1.f / __shfl(l, g * 4 + 2);
        float li3 = 1.f / __shfl(l, g * 4 + 3);
        size_t obase = (size_t)(b * S_LEN + qb * 64 + w * 16 + g * 4) * 512 + h * 128;
        #pragma unroll
        for (int cd = 0; cd < 8; cd++) {
            Ob[obase + 0 * 512 + cd * 16 + c15] = f2bf(o[cd][0] * li0);
            Ob[obase + 1 * 512 + cd * 16 + c15] = f2bf(o[cd][1] * li1);
            Ob[obase + 2 * 512 + cd * 16 + c15] = f2bf(o[cd][2] * li2);
            Ob[obase + 3 * 512 + cd * 16 + c15] = f2bf(o[cd][3] * li3);
        }
    } else {
        unsigned short* op = Opart + (size_t)split * 8192;
        int rb = w * 16 + g * 4;
        #pragma unroll
        for (int cd = 0; cd < 8; cd++) {
            op[(rb + 0) * 128 + cd * 16 + c15] = f2bf(o[cd][0]);
            op[(rb + 1) * 128 + cd * 16 + c15] = f2bf(o[cd][1]);
            op[(rb + 2) * 128 + cd * 16 + c15] = f2bf(o[cd][2]);
            op[(rb + 3) * 128 + cd * 16 + c15] = f2bf(o[cd][3]);
        }
        if (g == 0) {
            Mpart[split * 64 + w * 16 + c15] = m;
            Lpart[split * 64 + w * 16 + c15] = l;
        }
    }
}

// ---------------- merge split-K partials (qb 16..31) ----------------
__global__ __launch_bounds__(256) void attn_merge(
    const unsigned short* __restrict__ Opart,
    const float* __restrict__ Mpart, const float* __restrict__ Lpart,
    unsigned short* __restrict__ Ob)
{
    const float scale = 0.08838834764831845f;
    int bid = blockIdx.x;                 // bh*16 + (qb-16)
    int bh = bid >> 4, qe = bid & 15;
    int qb = 16 + qe;
    int b = bh >> 2, h = bh & 3;
    int p0 = bh * 32 + qe * 2;
    int t = threadIdx.x;
    int r = t >> 2, dq = t & 3;
    float m0 = Mpart[p0 * 64 + r], m1 = Mpart[(p0 + 1) * 64 + r];
    float l0 = Lpart[p0 * 64 + r], l1 = Lpart[(p0 + 1) * 64 + r];
    float ms = fmaxf(m0, m1);
    float w0 = __expf((m0 - ms) * scale), w1 = __expf((m1 - ms) * scale);
    float linv = 1.f / (l0 * w0 + l1 * w1);
    w0 *= linv; w1 *= linv;
    const unsigned short* o0 = Opart + (size_t)p0 * 8192 + r * 128 + dq * 32;
    const unsigned short* o1 = o0 + 8192;
    unsigned short* od = Ob + (size_t)(b * S_LEN + qb * 64 + r) * 512 + h * 128 + dq * 32;
    #pragma unroll
    for (int i = 0; i < 4; i++) {
        u16x8 a = *(const u16x8*)(o0 + i * 8);
        u16x8 c = *(const u16x8*)(o1 + i * 8);
        u16x8 d;
        #pragma unroll
        for (int j = 0; j < 8; j++)
            d[j] = f2bf(bf2f(a[j]) * w0 + bf2f(c[j]) * w1);
        *(u16x8*)(od + i * 8) = d;
    }
}

// ---------------- X = LayerNorm(X + D)*g + b ;  Xb = bf16(X) ----------------
// Wave-per-row: 4 rows/block, vectorized 16B loads, pure shfl reduce.
__global__ __launch_bounds__(256) void add_ln_kernel(
    float* __restrict__ X, const unsigned short* __restrict__ D,
    const float* __restrict__ gw, const float* __restrict__ bw,
    unsigned short* __restrict__ Xb)
{
    int wv = threadIdx.x >> 6, lane = threadIdx.x & 63;
    int row = blockIdx.x * 4 + wv;
    size_t base = (size_t)row * DMODEL + lane * 8;
    float4 x0 = *(const float4*)(X + base);
    float4 x1 = *(const float4*)(X + base + 4);
    u16x8 d8 = *(const u16x8*)(D + base);
    float v[8];
    v[0] = x0.x + bf2f(d8[0]); v[1] = x0.y + bf2f(d8[1]);
    v[2] = x0.z + bf2f(d8[2]); v[3] = x0.w + bf2f(d8[3]);
    v[4] = x1.x + bf2f(d8[4]); v[5] = x1.y + bf2f(d8[5]);
    v[6] = x1.z + bf2f(d8[6]); v[7] = x1.w + bf2f(d8[7]);
    float s = 0.f, sq = 0.f;
    #pragma unroll
    for (int i = 0; i < 8; i++) { s += v[i]; sq = fmaf(v[i], v[i], sq); }
    #pragma unroll
    for (int off = 32; off > 0; off >>= 1) {
        s  += __shfl_xor(s, off);
        sq += __shfl_xor(sq, off);
    }
    float mu = s * (1.f / DMODEL);
    float var = sq * (1.f / DMODEL) - mu * mu;
    float rs = rsqrtf(var + 1e-5f);
    float4 g0 = *(const float4*)(gw + lane * 8);
    float4 g1 = *(const float4*)(gw + lane * 8 + 4);
    float4 b0 = *(const float4*)(bw + lane * 8);
    float4 b1 = *(const float4*)(bw + lane * 8 + 4);
    float y[8];
    y[0] = (v[0] - mu) * rs * g0.x + b0.x; y[1] = (v[1] - mu) * rs * g0.y + b0.y;
    y[2] = (v[2] - mu) * rs * g0.z + b0.z; y[3] = (v[3] - mu) * rs * g0.w + b0.w;
    y[4] = (v[4] - mu) * rs * g1.x + b1.x; y[5] = (v[5] - mu) * rs * g1.y + b1.y;
    y[6] = (v[6] - mu) * rs * g1.z + b1.z; y[7] = (v[7] - mu) * rs * g1.w + b1.w;
    float4 o0 = { y[0], y[1], y[2], y[3] };
    float4 o1 = { y[4], y[5], y[6], y[7] };
    *(float4*)(X + base) = o0;
    *(float4*)(X + base + 4) = o1;
    u16x8 ob;
    #pragma unroll
    for (int i = 0; i < 8; i++) ob[i] = f2bf(y[i]);
    *(u16x8*)(Xb + base) = ob;
}

// ---------------- out = tanh(X @ dec_w^T + dec_b) * 10 ----------------
__global__ __launch_bounds__(256) void decoder_kernel(
    const float* __restrict__ X, const float* __restrict__ w,
    const float* __restrict__ bias, float* __restrict__ out)
{
    int tid = threadIdx.x;
    int lane = tid & 63;
    int row = blockIdx.x * 4 + (tid >> 6);
    float s = 0.f;
    size_t base = (size_t)row * DMODEL;
    #pragma unroll
    for (int i = 0; i < 8; i++) s = fmaf(X[base + lane + i * 64], w[lane + i * 64], s);
    #pragma unroll
    for (int off = 32; off > 0; off >>= 1) s += __shfl_down(s, off);
    if (lane == 0) out[row] = tanhf(s + bias[0]) * 10.0f;
}

extern "C" void kernel_launch(void* const* d_in, const int* in_sizes, int n_in,
                              void* d_out, int out_size, void* d_ws, size_t ws_size,
                              hipStream_t stream)
{
    const float* src   = (const float*)d_in[0];
    const float* emb_w = (const float*)d_in[1];
    const float* emb_b = (const float*)d_in[2];
    const float* in_w  = (const float*)d_in[3];
    const float* in_b  = (const float*)d_in[4];
    const float* out_w = (const float*)d_in[5];
    const float* out_b = (const float*)d_in[6];
    const float* ln1_g = (const float*)d_in[7];
    const float* ln1_b = (const float*)d_in[8];
    const float* ln2_g = (const float*)d_in[9];
    const float* ln2_b = (const float*)d_in[10];
    const float* ff1_w = (const float*)d_in[11];
    const float* ff1_b = (const float*)d_in[12];
    const float* ff2_w = (const float*)d_in[13];
    const float* ff2_b = (const float*)d_in[14];
    const float* dec_w = (const float*)d_in[15];
    const float* dec_b = (const float*)d_in[16];

    char* ws = (char*)d_ws;
    float*          X   = (float*)ws;                              // 16 MB
    unsigned short* Xb  = (unsigned short*)(ws + (16u << 20));     //  8 MB
    unsigned short* Pb  = (unsigned short*)(ws + (24u << 20));     //  8 MB
    unsigned short* Ob  = (unsigned short*)(ws + (32u << 20));     //  8 MB
    unsigned short* QKb = (unsigned short*)(ws + (40u << 20));     // 16 MB
    unsigned short* Vt  = (unsigned short*)(ws + (56u << 20));     //  8 MB
    unsigned short* Hb  = (unsigned short*)(ws + (40u << 20));     // 32 MB (overlaps QKb+Vt)
    // Attention split-K partials overlay regions that are DEAD during
    // flash+merge: Opart over Xb (rewritten by add_ln before next read),
    // Mpart/Lpart over Pb (written by O-proj after merge).
    unsigned short* Opart = (unsigned short*)(ws + (16u << 20));   // 512*8192 bf16 = 8 MB
    float* Mpart = (float*)(ws + (24u << 20));                     // 512*64 f32
    float* Lpart = Mpart + 512 * 64;
    unsigned short* in_wb  = (unsigned short*)(ws + (72u << 20));
    unsigned short* out_wb = in_wb  + 3u * 1536 * 512;
    unsigned short* ff1_wb = out_wb + 3u * 512 * 512;
    unsigned short* ff2_wb = ff1_wb + 3u * 2048 * 512;
    float* outp = (float*)d_out;
    const int M = 4 * S_LEN;   // 8192

    conv_all<<<9216, 256, 0, stream>>>(
        (const float4*)in_w, (const float4*)out_w,
        (const float4*)ff1_w, (const float4*)ff2_w,
        (u16x4*)in_wb, (u16x4*)out_wb, (u16x4*)ff1_wb, (u16x4*)ff2_wb);

    embed_kernel<<<M, 256, 0, stream>>>(src, emb_w, emb_b, X, Xb);

    for (int l = 0; l < 3; l++) {
        gemm_bf16<3, 128><<<dim3(768), 256, 0, stream>>>(
            Xb, 512, in_wb + (size_t)l * 1536 * 512, 512, in_b + l * 1536,
            QKb, 1024, Vt, 12);
        flash_attn<<<768, 256, 0, stream>>>(QKb, Vt, Ob, Opart, Mpart, Lpart);
        attn_merge<<<256, 256, 0, stream>>>(Opart, Mpart, Lpart, Ob);
        gemm_bf16<1, 64><<<dim3(512), 256, 0, stream>>>(
            Ob, 512, out_wb + (size_t)l * 512 * 512, 512, out_b + l * 512,
            Pb, 512, nullptr, 8);
        add_ln_kernel<<<M / 4, 256, 0, stream>>>(X, Pb, ln1_g + l * 512, ln1_b + l * 512, Xb);
        gemm_bf16<2, 128><<<dim3(1024), 256, 0, stream>>>(
            Xb, 512, ff1_wb + (size_t)l * 2048 * 512, 512, ff1_b + l * 2048,
            Hb, 2048, nullptr, 16);
        gemm_bf16<1, 64><<<dim3(512), 256, 0, stream>>>(
            Hb, 2048, ff2_wb + (size_t)l * 512 * 2048, 2048, ff2_b + l * 512,
            Pb, 512, nullptr, 8);
        add_ln_kernel<<<M / 4, 256, 0, stream>>>(X, Pb, ln2_g + l * 512, ln2_b + l * 512, Xb);
    }

    decoder_kernel<<<M / 4, 256, 0, stream>>>(X, dec_w, dec_b, outp);
}

// Round 13
// 504.300 us; speedup vs baseline: 1.1000x; 1.0253x over previous
//
#include <hip/hip_runtime.h>

#define S_LEN 2048
#define DMODEL 512

typedef __attribute__((ext_vector_type(8))) short bf16x8;
typedef __attribute__((ext_vector_type(4))) float f32x4;
typedef __attribute__((ext_vector_type(4))) unsigned short u16x4;
typedef __attribute__((ext_vector_type(8))) unsigned short u16x8;
typedef __attribute__((ext_vector_type(2))) unsigned int u32x2;

__device__ __forceinline__ unsigned short f2bf(float f) {
    unsigned int u = __float_as_uint(f);
    u += 0x7fff + ((u >> 16) & 1);            // RNE
    return (unsigned short)(u >> 16);
}
__device__ __forceinline__ float bf2f(unsigned short h) {
    return __uint_as_float(((unsigned int)h) << 16);
}
__device__ __forceinline__ void gll16(const void* g, void* l) {
    __builtin_amdgcn_global_load_lds(
        (const __attribute__((address_space(1))) unsigned int*)g,
        (__attribute__((address_space(3))) unsigned int*)l, 16, 0, 0);
}

// ---------------- fp32 -> bf16 bulk convert (all 4 weight tensors, 1 launch) ----------------
__global__ __launch_bounds__(256) void conv_all(
    const float4* __restrict__ in_w, const float4* __restrict__ out_w,
    const float4* __restrict__ ff1_w, const float4* __restrict__ ff2_w,
    u16x4* __restrict__ in_wb, u16x4* __restrict__ out_wb,
    u16x4* __restrict__ ff1_wb, u16x4* __restrict__ ff2_wb)
{
    int i = blockIdx.x * 256 + threadIdx.x;
    const float4* src; u16x4* dst; int j;
    if (i < 589824)        { src = in_w;  dst = in_wb;  j = i; }
    else if (i < 786432)   { src = out_w; dst = out_wb; j = i - 589824; }
    else if (i < 1572864)  { src = ff1_w; dst = ff1_wb; j = i - 786432; }
    else                   { src = ff2_w; dst = ff2_wb; j = i - 1572864; }
    float4 v = src[j];
    u16x4 o = { f2bf(v.x), f2bf(v.y), f2bf(v.z), f2bf(v.w) };
    dst[j] = o;
}

// ---------------- embedding + positional encoding ----------------
__global__ __launch_bounds__(256) void embed_kernel(
    const float* __restrict__ src, const float* __restrict__ ew,
    const float* __restrict__ eb, float* __restrict__ X,
    unsigned short* __restrict__ Xb)
{
    int rid = blockIdx.x;              // b*S + s
    int s = rid & (S_LEN - 1);
    int tid = threadIdx.x;
    __shared__ float sr[25];
    if (tid < 25) sr[tid] = src[rid * 25 + tid];
    __syncthreads();
    #pragma unroll
    for (int rep = 0; rep < 2; rep++) {
        int d = tid + rep * 256;
        float a = eb[d];
        #pragma unroll
        for (int k = 0; k < 25; k++) a = fmaf(sr[k], ew[d * 25 + k], a);
        int i2 = d & ~1;
        float div = expf(-(float)i2 * (9.210340371976184f / 512.f));
        float ang = (float)s * div;
        a += (d & 1) ? cosf(ang) : sinf(ang);
        X[(size_t)rid * DMODEL + d] = a;
        Xb[(size_t)rid * DMODEL + d] = f2bf(a);
    }
}

// ---------------- bf16 MFMA GEMM: C = A @ W^T + bias ----------------
// Double-buffered LDS pipeline with COUNTED vmcnt (T4): prefetch loads stay
// in flight across raw barriers (never drained to 0 in the main loop).
template<int MODE, int BN>
__global__ __launch_bounds__(256) void gemm_bf16(
    const unsigned short* __restrict__ A, int lda,
    const unsigned short* __restrict__ W, int K,
    const float* __restrict__ bias,
    unsigned short* __restrict__ out, int ldc,
    unsigned short* __restrict__ out2, int nbn)
{
    constexpr int NJ = BN / 32;
    constexpr int WC = BN / 2;                 // wave output cols
    __shared__ __align__(16) unsigned short LdsBuf[2][(128 + BN) * 64];
    int tid = threadIdx.x;
    int lane = tid & 63, w = tid >> 6;
    int g = lane >> 4, c15 = lane & 15;
    int wm = w >> 1, wn = w & 1;
    int bm, bn;
    if (BN == 64) {
        int raw = blockIdx.x;
        int lid = ((raw & 7) << 6) | (raw >> 3);  // consecutive lid -> same XCD
        bn = lid & 7; bm = lid >> 3;
    } else {
        int raw = blockIdx.x;
        int per = gridDim.x >> 3;                 // blocks per XCD chunk
        int lid = (raw & 7) * per + (raw >> 3);   // consecutive lid -> same XCD
        bn = lid % nbn; bm = lid / nbn;           // bn fastest: share A panel
    }

    f32x4 acc[4][NJ];
    #pragma unroll
    for (int i = 0; i < 4; i++)
        #pragma unroll
        for (int j = 0; j < NJ; j++) acc[i][j] = (f32x4){0.f, 0.f, 0.f, 0.f};

    auto stage = [&](int kk, int bi) {
        #pragma unroll
        for (int i = 0; i < 4; i++) {
            int chunk = tid + i * 256;
            int r = chunk >> 3, c = chunk & 7;
            int cs = c ^ (r & 7);
            gll16(A + (size_t)(bm * 128 + r) * lda + kk * 64 + cs * 8,
                  (void*)(LdsBuf[bi] + chunk * 8));
        }
        #pragma unroll
        for (int i = 0; i < BN / 32; i++) {
            int chunk = tid + i * 256;
            int r = chunk >> 3, c = chunk & 7;
            int cs = c ^ (r & 7);
            gll16(W + (size_t)(bn * BN + r) * K + kk * 64 + cs * 8,
                  (void*)(LdsBuf[bi] + 128 * 64 + chunk * 8));
        }
    };

    const int nk = K >> 6;
    stage(0, 0);
    int buf = 0;

    for (int kk = 0; kk < nk; kk++) {
        if (kk + 1 < nk) {
            stage(kk + 1, buf ^ 1);   // prefetch; stays in flight across barriers
            if constexpr (BN == 128) asm volatile("s_waitcnt vmcnt(8)" ::: "memory");
            else                     asm volatile("s_waitcnt vmcnt(6)" ::: "memory");
        } else {
            asm volatile("s_waitcnt vmcnt(0)" ::: "memory");
        }
        __builtin_amdgcn_s_barrier();          // current tile ready (counted wait)
        bf16x8 a[4][2], b[NJ][2];
        #pragma unroll
        for (int mi = 0; mi < 4; mi++) {
            int row = wm * 64 + mi * 16 + c15;
            #pragma unroll
            for (int h = 0; h < 2; h++) {
                int ck = (h * 4 + g) ^ (row & 7);
                a[mi][h] = *(const bf16x8*)((const char*)LdsBuf[buf] + row * 128 + ck * 16);
            }
        }
        #pragma unroll
        for (int nj = 0; nj < NJ; nj++) {
            int row = wn * WC + nj * 16 + c15;
            #pragma unroll
            for (int h = 0; h < 2; h++) {
                int ck = (h * 4 + g) ^ (row & 7);
                b[nj][h] = *(const bf16x8*)((const char*)(LdsBuf[buf] + 128 * 64)
                                            + row * 128 + ck * 16);
            }
        }
        __builtin_amdgcn_s_setprio(1);
        #pragma unroll
        for (int h = 0; h < 2; h++)
            #pragma unroll
            for (int mi = 0; mi < 4; mi++)
                #pragma unroll
                for (int nj = 0; nj < NJ; nj++)
                    acc[mi][nj] = __builtin_amdgcn_mfma_f32_16x16x32_bf16(
                        a[mi][h], b[nj][h], acc[mi][nj], 0, 0, 0);
        __builtin_amdgcn_s_setprio(0);
        __builtin_amdgcn_s_barrier();          // WAR: all waves done reading buf
        buf ^= 1;
    }
    __syncthreads();   // full sync before scratch overlays staging LDS

    // ---- per-wave LDS-transpose epilogue (staging LDS is dead past here) ----
    unsigned short* scr = (unsigned short*)LdsBuf + (size_t)w * 4608;  // [64][72]
    int colb0 = bn * BN + wn * WC;
    int rowb0 = bm * 128 + wm * 64;
    bool vout = (MODE == 3) && (colb0 >= 1024);
    #pragma unroll
    for (int nj = 0; nj < NJ; nj++) {
        float bv = bias[colb0 + nj * 16 + c15];
        #pragma unroll
        for (int mi = 0; mi < 4; mi++) {
            #pragma unroll
            for (int r = 0; r < 4; r++) {
                float v = acc[mi][nj][r] + bv;
                if (MODE == 2) v = fmaxf(v, 0.f);
                int rl = mi * 16 + g * 4 + r;
                int cl = nj * 16 + c15;
                if (!vout) scr[rl * 72 + cl] = f2bf(v);
                else       scr[cl * 72 + rl] = f2bf(v);   // transposed for V
            }
        }
    }
    // per-wave scratch: no barrier needed (compiler waits lgkmcnt on reads)
    constexpr int NP = WC / 8;        // 8 passes (BN=128) or 4 (BN=64)
    if (!vout) {
        #pragma unroll
        for (int p = 0; p < NP; p++) {
            int idx = p * 64 + lane;
            int row = idx / (WC / 8);
            int cc  = (idx % (WC / 8)) * 8;
            u16x8 v = *(const u16x8*)(scr + row * 72 + cc);
            *(u16x8*)(out + (size_t)(rowb0 + row) * ldc + colb0 + cc) = v;
        }
    } else {
        int cv0 = colb0 - 1024;                   // multiple of 64
        int hh = cv0 >> 7, d0 = cv0 & 127;
        int bb = rowb0 >> 11, t0 = rowb0 & (S_LEN - 1);
        unsigned short* vbase = out2 + ((size_t)(bb * 4 + hh) * 128 + d0) * S_LEN + t0;
        #pragma unroll
        for (int p = 0; p < 8; p++) {
            int idx = p * 64 + lane;
            int rd = idx >> 3;                    // d offset 0..63
            int tc = (idx & 7) * 8;               // t offset
            u16x8 v = *(const u16x8*)(scr + rd * 72 + tc);
            *(u16x8*)(vbase + (size_t)rd * S_LEN + tc) = v;
        }
    }
}

// ---------------- bf16 MFMA flash attention ----------------
// KVBLK=32, split-K for qb>=16, double-buffered staging with COUNTED vmcnt:
// prefetch loads ride across both raw barriers (no vmcnt(0) drain in loop).
__global__ __launch_bounds__(256) void flash_attn(
    const unsigned short* __restrict__ QKb,
    const unsigned short* __restrict__ Vt,
    unsigned short* __restrict__ Ob,
    unsigned short* __restrict__ Opart,   // [512][64*128] bf16
    float* __restrict__ Mpart,            // [512][64]
    float* __restrict__ Lpart)            // [512][64]
{
    __shared__ __align__(16) unsigned short Ks[2][32 * 128];
    __shared__ __align__(16) unsigned short Vts[2][128 * 32];
    __shared__ __align__(16) unsigned short Plds[4][16 * 40];   // stride 40 u16
    const float scale = 0.08838834764831845f;   // 1/sqrt(128)
    int tid = threadIdx.x;
    int lane = tid & 63, w = tid >> 6;
    int g = lane >> 4, c15 = lane & 15;
    int raw = blockIdx.x;
    int lid = (raw & 7) * 96 + (raw >> 3);       // XCD-chunked (768 = 8*96)
    int bh = lid / 48, idx = lid - bh * 48;
    int b = bh >> 2, h = bh & 3;
    // 32-token KV tiles: qb has 2qb+2 tiles total.
    int qb, kt0, nkt, split;
    if (idx < 16) { qb = idx; kt0 = 0; nkt = 2 * qb + 2; split = -1; }
    else {
        int s = idx - 16;
        qb = 16 + (s >> 1);
        int j = s & 1;
        kt0 = j * (qb + 1);
        nkt = qb + 1;
        split = bh * 32 + (qb - 16) * 2 + j;
    }

    // Q fragments (B-operand): this lane's q-row = qb*64 + w*16 + c15
    bf16x8 q[4];
    {
        const unsigned short* qrow =
            QKb + (size_t)(b * S_LEN + qb * 64 + w * 16 + c15) * 1024 + h * 128;
        #pragma unroll
        for (int k0 = 0; k0 < 4; k0++) q[k0] = *(const bf16x8*)(qrow + k0 * 32 + g * 8);
    }
    f32x4 o[8];
    #pragma unroll
    for (int cd = 0; cd < 8; cd++) o[cd] = (f32x4){0.f, 0.f, 0.f, 0.f};
    float m = -3e38f, l = 0.f;

    auto stage = [&](int kt, int bi) {
        #pragma unroll
        for (int i = 0; i < 2; i++) {      // K tile: 32 rows x 16 chunks (swizzled src)
            int chunk = tid + i * 256;
            int r = chunk >> 4, c = chunk & 15;
            int cs = (c & 8) | ((c ^ r) & 7);
            gll16(QKb + (size_t)(b * S_LEN + kt * 32 + r) * 1024 + 512 + h * 128 + cs * 8,
                  (void*)(Ks[bi] + chunk * 8));
        }
        #pragma unroll
        for (int i = 0; i < 2; i++) {      // Vt tile: 128 rows x 4 chunks
            int chunk = tid + i * 256;
            int r = chunk >> 2, c = chunk & 3;
            int cs = (c ^ r) & 3;
            gll16(Vt + ((size_t)(b * 4 + h) * 128 + r) * S_LEN + kt * 32 + cs * 8,
                  (void*)(Vts[bi] + chunk * 8));
        }
    };

    stage(kt0, 0);
    int buf = 0;

    for (int t = 0; t < nkt; t++) {
        int kt = kt0 + t;
        if (t + 1 < nkt) {
            stage(kt + 1, buf ^ 1);   // prefetch; stays in flight across barriers
            asm volatile("s_waitcnt vmcnt(4)" ::: "memory");
        } else {
            asm volatile("s_waitcnt vmcnt(0)" ::: "memory");
        }
        __builtin_amdgcn_s_barrier();          // current tile ready (counted wait)
        // --- S^T = K Q^T (swapped): lane holds q-row c15, tokens c*16+g*4+r ---
        f32x4 sf[2];
        __builtin_amdgcn_s_setprio(1);
        #pragma unroll
        for (int c = 0; c < 2; c++) {
            sf[c] = (f32x4){0.f, 0.f, 0.f, 0.f};
            int tok16 = c * 16 + c15;
            #pragma unroll
            for (int k0 = 0; k0 < 4; k0++) {
                int ck = k0 * 4 + g;
                int cs = (ck & 8) | ((ck ^ tok16) & 7);
                bf16x8 kf = *(const bf16x8*)((const char*)Ks[buf] + tok16 * 256 + cs * 16);
                sf[c] = __builtin_amdgcn_mfma_f32_16x16x32_bf16(kf, q[k0], sf[c], 0, 0, 0);
            }
        }
        __builtin_amdgcn_s_setprio(0);
        // --- mask: last two tiles only (incl. PRE block) ---
        if (kt >= 2 * qb) {
            int qr = qb * 64 + w * 16 + c15;
            #pragma unroll
            for (int c = 0; c < 2; c++)
                #pragma unroll
                for (int r = 0; r < 4; r++) {
                    int tok = kt * 32 + c * 16 + g * 4 + r;
                    bool ok = (tok <= qr) || (qr < 20 && tok < 20);
                    if (!ok) sf[c][r] = -3e38f;
                }
        }
        // --- row max: in-lane tree + 2 shfl ---
        float t0 = fmaxf(fmaxf(sf[0][0], sf[0][1]), fmaxf(sf[0][2], sf[0][3]));
        float t1 = fmaxf(fmaxf(sf[1][0], sf[1][1]), fmaxf(sf[1][2], sf[1][3]));
        float mt = fmaxf(t0, t1);
        mt = fmaxf(mt, __shfl_xor(mt, 16));
        mt = fmaxf(mt, __shfl_xor(mt, 32));
        // --- defer-max (T13): 8 nats = 90.5 raw ---
        bool need = !__all(mt <= m + 90.5f);
        float sc = 1.f;
        if (need) {
            float mn = fmaxf(m, mt);
            sc = __expf((m - mn) * scale);
            m = mn;
        }
        float msc = m * scale;
        #pragma unroll
        for (int c = 0; c < 2; c++)
            #pragma unroll
            for (int r = 0; r < 4; r++)
                sf[c][r] = __expf(fmaf(sf[c][r], scale, -msc));
        float s0 = (sf[0][0] + sf[0][1]) + (sf[0][2] + sf[0][3]);
        float s1 = (sf[1][0] + sf[1][1]) + (sf[1][2] + sf[1][3]);
        float ls = s0 + s1;
        ls += __shfl_xor(ls, 16);
        ls += __shfl_xor(ls, 32);
        if (need) l *= sc;
        l += ls;
        // --- P -> Plds[q-row][token], packed b64 writes ---
        #pragma unroll
        for (int c = 0; c < 2; c++) {
            unsigned int lo = ((unsigned int)f2bf(sf[c][1]) << 16) | f2bf(sf[c][0]);
            unsigned int hi = ((unsigned int)f2bf(sf[c][3]) << 16) | f2bf(sf[c][2]);
            u32x2 pk = {lo, hi};
            *(u32x2*)&Plds[w][c15 * 40 + c * 16 + g * 4] = pk;
        }
        // --- rescale O (skipped when deferred) ---
        if (need) {
            float r0 = __shfl(sc, g * 4 + 0);
            float r1 = __shfl(sc, g * 4 + 1);
            float r2 = __shfl(sc, g * 4 + 2);
            float r3 = __shfl(sc, g * 4 + 3);
            #pragma unroll
            for (int cd = 0; cd < 8; cd++) {
                o[cd][0] *= r0; o[cd][1] *= r1; o[cd][2] *= r2; o[cd][3] *= r3;
            }
        }
        // --- O += P V (single K=32 MFMA per d-group) ---
        bf16x8 pa = *(const bf16x8*)((const char*)&Plds[w][0] + c15 * 80 + g * 16);
        __builtin_amdgcn_s_setprio(1);
        #pragma unroll
        for (int cd = 0; cd < 8; cd++) {
            int dv = cd * 16 + c15;
            int cs = (g ^ dv) & 3;
            bf16x8 vf = *(const bf16x8*)((const char*)Vts[buf] + dv * 64 + cs * 16);
            o[cd] = __builtin_amdgcn_mfma_f32_16x16x32_bf16(pa, vf, o[cd], 0, 0, 0);
        }
        __builtin_amdgcn_s_setprio(0);
        __builtin_amdgcn_s_barrier();          // WAR: all waves done reading buf
        buf ^= 1;
    }

    if (split < 0) {
        float li0 = 1.f / __shfl(l, g * 4 + 0);
        float li1 = 1.f / __shfl(l, g * 4 + 1);
        float li2 = 1.f / __shfl(l, g * 4 + 2);
        float li3 = 1.f / __shfl(l, g * 4 + 3);
        size_t obase = (size_t)(b * S_LEN + qb * 64 + w * 16 + g * 4) * 512 + h * 128;
        #pragma unroll
        for (int cd = 0; cd < 8; cd++) {
            Ob[obase + 0 * 512 + cd * 16 + c15] = f2bf(o[cd][0] * li0);
            Ob[obase + 1 * 512 + cd * 16 + c15] = f2bf(o[cd][1] * li1);
            Ob[obase + 2 * 512 + cd * 16 + c15] = f2bf(o[cd][2] * li2);
            Ob[obase + 3 * 512 + cd * 16 + c15] = f2bf(o[cd][3] * li3);
        }
    } else {
        unsigned short* op = Opart + (size_t)split * 8192;
        int rb = w * 16 + g * 4;
        #pragma unroll
        for (int cd = 0; cd < 8; cd++) {
            op[(rb + 0) * 128 + cd * 16 + c15] = f2bf(o[cd][0]);
            op[(rb + 1) * 128 + cd * 16 + c15] = f2bf(o[cd][1]);
            op[(rb + 2) * 128 + cd * 16 + c15] = f2bf(o[cd][2]);
            op[(rb + 3) * 128 + cd * 16 + c15] = f2bf(o[cd][3]);
        }
        if (g == 0) {
            Mpart[split * 64 + w * 16 + c15] = m;
            Lpart[split * 64 + w * 16 + c15] = l;
        }
    }
}

// ---------------- merge split-K partials (qb 16..31) ----------------
__global__ __launch_bounds__(256) void attn_merge(
    const unsigned short* __restrict__ Opart,
    const float* __restrict__ Mpart, const float* __restrict__ Lpart,
    unsigned short* __restrict__ Ob)
{
    const float scale = 0.08838834764831845f;
    int bid = blockIdx.x;                 // bh*16 + (qb-16)
    int bh = bid >> 4, qe = bid & 15;
    int qb = 16 + qe;
    int b = bh >> 2, h = bh & 3;
    int p0 = bh * 32 + qe * 2;
    int t = threadIdx.x;
    int r = t >> 2, dq = t & 3;
    float m0 = Mpart[p0 * 64 + r], m1 = Mpart[(p0 + 1) * 64 + r];
    float l0 = Lpart[p0 * 64 + r], l1 = Lpart[(p0 + 1) * 64 + r];
    float ms = fmaxf(m0, m1);
    float w0 = __expf((m0 - ms) * scale), w1 = __expf((m1 - ms) * scale);
    float linv = 1.f / (l0 * w0 + l1 * w1);
    w0 *= linv; w1 *= linv;
    const unsigned short* o0 = Opart + (size_t)p0 * 8192 + r * 128 + dq * 32;
    const unsigned short* o1 = o0 + 8192;
    unsigned short* od = Ob + (size_t)(b * S_LEN + qb * 64 + r) * 512 + h * 128 + dq * 32;
    #pragma unroll
    for (int i = 0; i < 4; i++) {
        u16x8 a = *(const u16x8*)(o0 + i * 8);
        u16x8 c = *(const u16x8*)(o1 + i * 8);
        u16x8 d;
        #pragma unroll
        for (int j = 0; j < 8; j++)
            d[j] = f2bf(bf2f(a[j]) * w0 + bf2f(c[j]) * w1);
        *(u16x8*)(od + i * 8) = d;
    }
}

// ---------------- X = LayerNorm(X + D)*g + b ;  Xb = bf16(X) ----------------
// Wave-per-row: 4 rows/block, vectorized 16B loads, pure shfl reduce.
__global__ __launch_bounds__(256) void add_ln_kernel(
    float* __restrict__ X, const unsigned short* __restrict__ D,
    const float* __restrict__ gw, const float* __restrict__ bw,
    unsigned short* __restrict__ Xb)
{
    int wv = threadIdx.x >> 6, lane = threadIdx.x & 63;
    int row = blockIdx.x * 4 + wv;
    size_t base = (size_t)row * DMODEL + lane * 8;
    float4 x0 = *(const float4*)(X + base);
    float4 x1 = *(const float4*)(X + base + 4);
    u16x8 d8 = *(const u16x8*)(D + base);
    float v[8];
    v[0] = x0.x + bf2f(d8[0]); v[1] = x0.y + bf2f(d8[1]);
    v[2] = x0.z + bf2f(d8[2]); v[3] = x0.w + bf2f(d8[3]);
    v[4] = x1.x + bf2f(d8[4]); v[5] = x1.y + bf2f(d8[5]);
    v[6] = x1.z + bf2f(d8[6]); v[7] = x1.w + bf2f(d8[7]);
    float s = 0.f, sq = 0.f;
    #pragma unroll
    for (int i = 0; i < 8; i++) { s += v[i]; sq = fmaf(v[i], v[i], sq); }
    #pragma unroll
    for (int off = 32; off > 0; off >>= 1) {
        s  += __shfl_xor(s, off);
        sq += __shfl_xor(sq, off);
    }
    float mu = s * (1.f / DMODEL);
    float var = sq * (1.f / DMODEL) - mu * mu;
    float rs = rsqrtf(var + 1e-5f);
    float4 g0 = *(const float4*)(gw + lane * 8);
    float4 g1 = *(const float4*)(gw + lane * 8 + 4);
    float4 b0 = *(const float4*)(bw + lane * 8);
    float4 b1 = *(const float4*)(bw + lane * 8 + 4);
    float y[8];
    y[0] = (v[0] - mu) * rs * g0.x + b0.x; y[1] = (v[1] - mu) * rs * g0.y + b0.y;
    y[2] = (v[2] - mu) * rs * g0.z + b0.z; y[3] = (v[3] - mu) * rs * g0.w + b0.w;
    y[4] = (v[4] - mu) * rs * g1.x + b1.x; y[5] = (v[5] - mu) * rs * g1.y + b1.y;
    y[6] = (v[6] - mu) * rs * g1.z + b1.z; y[7] = (v[7] - mu) * rs * g1.w + b1.w;
    float4 o0 = { y[0], y[1], y[2], y[3] };
    float4 o1 = { y[4], y[5], y[6], y[7] };
    *(float4*)(X + base) = o0;
    *(float4*)(X + base + 4) = o1;
    u16x8 ob;
    #pragma unroll
    for (int i = 0; i < 8; i++) ob[i] = f2bf(y[i]);
    *(u16x8*)(Xb + base) = ob;
}

// ---------------- out = tanh(X @ dec_w^T + dec_b) * 10 ----------------
__global__ __launch_bounds__(256) void decoder_kernel(
    const float* __restrict__ X, const float* __restrict__ w,
    const float* __restrict__ bias, float* __restrict__ out)
{
    int tid = threadIdx.x;
    int lane = tid & 63;
    int row = blockIdx.x * 4 + (tid >> 6);
    float s = 0.f;
    size_t base = (size_t)row * DMODEL;
    #pragma unroll
    for (int i = 0; i < 8; i++) s = fmaf(X[base + lane + i * 64], w[lane + i * 64], s);
    #pragma unroll
    for (int off = 32; off > 0; off >>= 1) s += __shfl_down(s, off);
    if (lane == 0) out[row] = tanhf(s + bias[0]) * 10.0f;
}

extern "C" void kernel_launch(void* const* d_in, const int* in_sizes, int n_in,
                              void* d_out, int out_size, void* d_ws, size_t ws_size,
                              hipStream_t stream)
{
    const float* src   = (const float*)d_in[0];
    const float* emb_w = (const float*)d_in[1];
    const float* emb_b = (const float*)d_in[2];
    const float* in_w  = (const float*)d_in[3];
    const float* in_b  = (const float*)d_in[4];
    const float* out_w = (const float*)d_in[5];
    const float* out_b = (const float*)d_in[6];
    const float* ln1_g = (const float*)d_in[7];
    const float* ln1_b = (const float*)d_in[8];
    const float* ln2_g = (const float*)d_in[9];
    const float* ln2_b = (const float*)d_in[10];
    const float* ff1_w = (const float*)d_in[11];
    const float* ff1_b = (const float*)d_in[12];
    const float* ff2_w = (const float*)d_in[13];
    const float* ff2_b = (const float*)d_in[14];
    const float* dec_w = (const float*)d_in[15];
    const float* dec_b = (const float*)d_in[16];

    char* ws = (char*)d_ws;
    float*          X   = (float*)ws;                              // 16 MB
    unsigned short* Xb  = (unsigned short*)(ws + (16u << 20));     //  8 MB
    unsigned short* Pb  = (unsigned short*)(ws + (24u << 20));     //  8 MB
    unsigned short* Ob  = (unsigned short*)(ws + (32u << 20));     //  8 MB
    unsigned short* QKb = (unsigned short*)(ws + (40u << 20));     // 16 MB
    unsigned short* Vt  = (unsigned short*)(ws + (56u << 20));     //  8 MB
    unsigned short* Hb  = (unsigned short*)(ws + (40u << 20));     // 32 MB (overlaps QKb+Vt)
    // Attention split-K partials overlay regions that are DEAD during
    // flash+merge: Opart over Xb (rewritten by add_ln before next read),
    // Mpart/Lpart over Pb (written by O-proj after merge).
    unsigned short* Opart = (unsigned short*)(ws + (16u << 20));   // 512*8192 bf16 = 8 MB
    float* Mpart = (float*)(ws + (24u << 20));                     // 512*64 f32
    float* Lpart = Mpart + 512 * 64;
    unsigned short* in_wb  = (unsigned short*)(ws + (72u << 20));
    unsigned short* out_wb = in_wb  + 3u * 1536 * 512;
    unsigned short* ff1_wb = out_wb + 3u * 512 * 512;
    unsigned short* ff2_wb = ff1_wb + 3u * 2048 * 512;
    float* outp = (float*)d_out;
    const int M = 4 * S_LEN;   // 8192

    conv_all<<<9216, 256, 0, stream>>>(
        (const float4*)in_w, (const float4*)out_w,
        (const float4*)ff1_w, (const float4*)ff2_w,
        (u16x4*)in_wb, (u16x4*)out_wb, (u16x4*)ff1_wb, (u16x4*)ff2_wb);

    embed_kernel<<<M, 256, 0, stream>>>(src, emb_w, emb_b, X, Xb);

    for (int l = 0; l < 3; l++) {
        gemm_bf16<3, 128><<<dim3(768), 256, 0, stream>>>(
            Xb, 512, in_wb + (size_t)l * 1536 * 512, 512, in_b + l * 1536,
            QKb, 1024, Vt, 12);
        flash_attn<<<768, 256, 0, stream>>>(QKb, Vt, Ob, Opart, Mpart, Lpart);
        attn_merge<<<256, 256, 0, stream>>>(Opart, Mpart, Lpart, Ob);
        gemm_bf16<1, 64><<<dim3(512), 256, 0, stream>>>(
            Ob, 512, out_wb + (size_t)l * 512 * 512, 512, out_b + l * 512,
            Pb, 512, nullptr, 8);
        add_ln_kernel<<<M / 4, 256, 0, stream>>>(X, Pb, ln1_g + l * 512, ln1_b + l * 512, Xb);
        gemm_bf16<2, 128><<<dim3(1024), 256, 0, stream>>>(
            Xb, 512, ff1_wb + (size_t)l * 2048 * 512, 512, ff1_b + l * 2048,
            Hb, 2048, nullptr, 16);
        gemm_bf16<1, 64><<<dim3(512), 256, 0, stream>>>(
            Hb, 2048, ff2_wb + (size_t)l * 512 * 2048, 2048, ff2_b + l * 512,
            Pb, 512, nullptr, 8);
        add_ln_kernel<<<M / 4, 256, 0, stream>>>(X, Pb, ln2_g + l * 512, ln2_b + l * 512, Xb);
    }

    decoder_kernel<<<M / 4, 256, 0, stream>>>(X, dec_w, dec_b, outp);
}

// Round 14
// 497.045 us; speedup vs baseline: 1.1161x; 1.0146x over previous
//
#include <hip/hip_runtime.h>

#define S_LEN 2048
#define DMODEL 512

typedef __attribute__((ext_vector_type(8))) short bf16x8;
typedef __attribute__((ext_vector_type(4))) float f32x4;
typedef __attribute__((ext_vector_type(4))) unsigned short u16x4;
typedef __attribute__((ext_vector_type(8))) unsigned short u16x8;
typedef __attribute__((ext_vector_type(2))) unsigned int u32x2;

__device__ __forceinline__ unsigned short f2bf(float f) {
    unsigned int u = __float_as_uint(f);
    u += 0x7fff + ((u >> 16) & 1);            // RNE
    return (unsigned short)(u >> 16);
}
__device__ __forceinline__ float bf2f(unsigned short h) {
    return __uint_as_float(((unsigned int)h) << 16);
}
__device__ __forceinline__ unsigned int cvtpk(float lo, float hi) {
    unsigned int r;
    asm("v_cvt_pk_bf16_f32 %0, %1, %2" : "=v"(r) : "v"(lo), "v"(hi));
    return r;
}
__device__ __forceinline__ void gll16(const void* g, void* l) {
    __builtin_amdgcn_global_load_lds(
        (const __attribute__((address_space(1))) unsigned int*)g,
        (__attribute__((address_space(3))) unsigned int*)l, 16, 0, 0);
}

// ---------------- fp32 -> bf16 bulk convert (all 4 weight tensors, 1 launch) ----------------
__global__ __launch_bounds__(256) void conv_all(
    const float4* __restrict__ in_w, const float4* __restrict__ out_w,
    const float4* __restrict__ ff1_w, const float4* __restrict__ ff2_w,
    u16x4* __restrict__ in_wb, u16x4* __restrict__ out_wb,
    u16x4* __restrict__ ff1_wb, u16x4* __restrict__ ff2_wb)
{
    int i = blockIdx.x * 256 + threadIdx.x;
    const float4* src; u16x4* dst; int j;
    if (i < 589824)        { src = in_w;  dst = in_wb;  j = i; }
    else if (i < 786432)   { src = out_w; dst = out_wb; j = i - 589824; }
    else if (i < 1572864)  { src = ff1_w; dst = ff1_wb; j = i - 786432; }
    else                   { src = ff2_w; dst = ff2_wb; j = i - 1572864; }
    float4 v = src[j];
    u16x4 o = { f2bf(v.x), f2bf(v.y), f2bf(v.z), f2bf(v.w) };
    dst[j] = o;
}

// ---------------- embedding + positional encoding ----------------
__global__ __launch_bounds__(256) void embed_kernel(
    const float* __restrict__ src, const float* __restrict__ ew,
    const float* __restrict__ eb, float* __restrict__ X,
    unsigned short* __restrict__ Xb)
{
    int rid = blockIdx.x;              // b*S + s
    int s = rid & (S_LEN - 1);
    int tid = threadIdx.x;
    __shared__ float sr[25];
    if (tid < 25) sr[tid] = src[rid * 25 + tid];
    __syncthreads();
    #pragma unroll
    for (int rep = 0; rep < 2; rep++) {
        int d = tid + rep * 256;
        float a = eb[d];
        #pragma unroll
        for (int k = 0; k < 25; k++) a = fmaf(sr[k], ew[d * 25 + k], a);
        int i2 = d & ~1;
        float div = expf(-(float)i2 * (9.210340371976184f / 512.f));
        float ang = (float)s * div;
        a += (d & 1) ? cosf(ang) : sinf(ang);
        X[(size_t)rid * DMODEL + d] = a;
        Xb[(size_t)rid * DMODEL + d] = f2bf(a);
    }
}

// ---------------- bf16 MFMA GEMM: C = A @ W^T + bias ----------------
// Double-buffered LDS pipeline with COUNTED vmcnt (T4): prefetch loads stay
// in flight across raw barriers (never drained to 0 in the main loop).
template<int MODE, int BN>
__global__ __launch_bounds__(256) void gemm_bf16(
    const unsigned short* __restrict__ A, int lda,
    const unsigned short* __restrict__ W, int K,
    const float* __restrict__ bias,
    unsigned short* __restrict__ out, int ldc,
    unsigned short* __restrict__ out2, int nbn)
{
    constexpr int NJ = BN / 32;
    constexpr int WC = BN / 2;                 // wave output cols
    __shared__ __align__(16) unsigned short LdsBuf[2][(128 + BN) * 64];
    int tid = threadIdx.x;
    int lane = tid & 63, w = tid >> 6;
    int g = lane >> 4, c15 = lane & 15;
    int wm = w >> 1, wn = w & 1;
    int bm, bn;
    if (BN == 64) {
        int raw = blockIdx.x;
        int lid = ((raw & 7) << 6) | (raw >> 3);  // consecutive lid -> same XCD
        bn = lid & 7; bm = lid >> 3;
    } else {
        int raw = blockIdx.x;
        int per = gridDim.x >> 3;                 // blocks per XCD chunk
        int lid = (raw & 7) * per + (raw >> 3);   // consecutive lid -> same XCD
        bn = lid % nbn; bm = lid / nbn;           // bn fastest: share A panel
    }

    f32x4 acc[4][NJ];
    #pragma unroll
    for (int i = 0; i < 4; i++)
        #pragma unroll
        for (int j = 0; j < NJ; j++) acc[i][j] = (f32x4){0.f, 0.f, 0.f, 0.f};

    auto stage = [&](int kk, int bi) {
        #pragma unroll
        for (int i = 0; i < 4; i++) {
            int chunk = tid + i * 256;
            int r = chunk >> 3, c = chunk & 7;
            int cs = c ^ (r & 7);
            gll16(A + (size_t)(bm * 128 + r) * lda + kk * 64 + cs * 8,
                  (void*)(LdsBuf[bi] + chunk * 8));
        }
        #pragma unroll
        for (int i = 0; i < BN / 32; i++) {
            int chunk = tid + i * 256;
            int r = chunk >> 3, c = chunk & 7;
            int cs = c ^ (r & 7);
            gll16(W + (size_t)(bn * BN + r) * K + kk * 64 + cs * 8,
                  (void*)(LdsBuf[bi] + 128 * 64 + chunk * 8));
        }
    };

    const int nk = K >> 6;
    stage(0, 0);
    int buf = 0;

    for (int kk = 0; kk < nk; kk++) {
        if (kk + 1 < nk) {
            stage(kk + 1, buf ^ 1);   // prefetch; stays in flight across barriers
            if constexpr (BN == 128) asm volatile("s_waitcnt vmcnt(8)" ::: "memory");
            else                     asm volatile("s_waitcnt vmcnt(6)" ::: "memory");
        } else {
            asm volatile("s_waitcnt vmcnt(0)" ::: "memory");
        }
        __builtin_amdgcn_s_barrier();          // current tile ready (counted wait)
        bf16x8 a[4][2], b[NJ][2];
        #pragma unroll
        for (int mi = 0; mi < 4; mi++) {
            int row = wm * 64 + mi * 16 + c15;
            #pragma unroll
            for (int h = 0; h < 2; h++) {
                int ck = (h * 4 + g) ^ (row & 7);
                a[mi][h] = *(const bf16x8*)((const char*)LdsBuf[buf] + row * 128 + ck * 16);
            }
        }
        #pragma unroll
        for (int nj = 0; nj < NJ; nj++) {
            int row = wn * WC + nj * 16 + c15;
            #pragma unroll
            for (int h = 0; h < 2; h++) {
                int ck = (h * 4 + g) ^ (row & 7);
                b[nj][h] = *(const bf16x8*)((const char*)(LdsBuf[buf] + 128 * 64)
                                            + row * 128 + ck * 16);
            }
        }
        __builtin_amdgcn_s_setprio(1);
        #pragma unroll
        for (int h = 0; h < 2; h++)
            #pragma unroll
            for (int mi = 0; mi < 4; mi++)
                #pragma unroll
                for (int nj = 0; nj < NJ; nj++)
                    acc[mi][nj] = __builtin_amdgcn_mfma_f32_16x16x32_bf16(
                        a[mi][h], b[nj][h], acc[mi][nj], 0, 0, 0);
        __builtin_amdgcn_s_setprio(0);
        __builtin_amdgcn_s_barrier();          // WAR: all waves done reading buf
        buf ^= 1;
    }
    __syncthreads();   // full sync before scratch overlays staging LDS

    // ---- per-wave LDS-transpose epilogue (staging LDS is dead past here) ----
    unsigned short* scr = (unsigned short*)LdsBuf + (size_t)w * 4608;  // [64][72]
    int colb0 = bn * BN + wn * WC;
    int rowb0 = bm * 128 + wm * 64;
    bool vout = (MODE == 3) && (colb0 >= 1024);
    #pragma unroll
    for (int nj = 0; nj < NJ; nj++) {
        float bv = bias[colb0 + nj * 16 + c15];
        #pragma unroll
        for (int mi = 0; mi < 4; mi++) {
            #pragma unroll
            for (int r = 0; r < 4; r++) {
                float v = acc[mi][nj][r] + bv;
                if (MODE == 2) v = fmaxf(v, 0.f);
                int rl = mi * 16 + g * 4 + r;
                int cl = nj * 16 + c15;
                if (!vout) scr[rl * 72 + cl] = f2bf(v);
                else       scr[cl * 72 + rl] = f2bf(v);   // transposed for V
            }
        }
    }
    // per-wave scratch: no barrier needed (compiler waits lgkmcnt on reads)
    constexpr int NP = WC / 8;        // 8 passes (BN=128) or 4 (BN=64)
    if (!vout) {
        #pragma unroll
        for (int p = 0; p < NP; p++) {
            int idx = p * 64 + lane;
            int row = idx / (WC / 8);
            int cc  = (idx % (WC / 8)) * 8;
            u16x8 v = *(const u16x8*)(scr + row * 72 + cc);
            *(u16x8*)(out + (size_t)(rowb0 + row) * ldc + colb0 + cc) = v;
        }
    } else {
        int cv0 = colb0 - 1024;                   // multiple of 64
        int hh = cv0 >> 7, d0 = cv0 & 127;
        int bb = rowb0 >> 11, t0 = rowb0 & (S_LEN - 1);
        unsigned short* vbase = out2 + ((size_t)(bb * 4 + hh) * 128 + d0) * S_LEN + t0;
        #pragma unroll
        for (int p = 0; p < 8; p++) {
            int idx = p * 64 + lane;
            int rd = idx >> 3;                    // d offset 0..63
            int tc = (idx & 7) * 8;               // t offset
            u16x8 v = *(const u16x8*)(scr + rd * 72 + tc);
            *(u16x8*)(vbase + (size_t)rd * S_LEN + tc) = v;
        }
    }
}

// ---------------- bf16 MFMA flash attention ----------------
// KVBLK=32, split-K for qb>=16, counted-vmcnt double-buffer staging.
// exp2-domain softmax (raw-score m state) + v_cvt_pk_bf16_f32 P-pack.
__global__ __launch_bounds__(256) void flash_attn(
    const unsigned short* __restrict__ QKb,
    const unsigned short* __restrict__ Vt,
    unsigned short* __restrict__ Ob,
    unsigned short* __restrict__ Opart,   // [512][64*128] bf16
    float* __restrict__ Mpart,            // [512][64]
    float* __restrict__ Lpart)            // [512][64]
{
    __shared__ __align__(16) unsigned short Ks[2][32 * 128];
    __shared__ __align__(16) unsigned short Vts[2][128 * 32];
    __shared__ __align__(16) unsigned short Plds[4][16 * 40];   // stride 40 u16
    const float SCL2 = 0.12751742795f;    // (1/sqrt(128)) * log2(e)
    int tid = threadIdx.x;
    int lane = tid & 63, w = tid >> 6;
    int g = lane >> 4, c15 = lane & 15;
    int raw = blockIdx.x;
    int lid = (raw & 7) * 96 + (raw >> 3);       // XCD-chunked (768 = 8*96)
    int bh = lid / 48, idx = lid - bh * 48;
    int b = bh >> 2, h = bh & 3;
    // 32-token KV tiles: qb has 2qb+2 tiles total.
    int qb, kt0, nkt, split;
    if (idx < 16) { qb = idx; kt0 = 0; nkt = 2 * qb + 2; split = -1; }
    else {
        int s = idx - 16;
        qb = 16 + (s >> 1);
        int j = s & 1;
        kt0 = j * (qb + 1);
        nkt = qb + 1;
        split = bh * 32 + (qb - 16) * 2 + j;
    }

    // Q fragments (B-operand): this lane's q-row = qb*64 + w*16 + c15
    bf16x8 q[4];
    {
        const unsigned short* qrow =
            QKb + (size_t)(b * S_LEN + qb * 64 + w * 16 + c15) * 1024 + h * 128;
        #pragma unroll
        for (int k0 = 0; k0 < 4; k0++) q[k0] = *(const bf16x8*)(qrow + k0 * 32 + g * 8);
    }
    f32x4 o[8];
    #pragma unroll
    for (int cd = 0; cd < 8; cd++) o[cd] = (f32x4){0.f, 0.f, 0.f, 0.f};
    float m = -3e38f, l = 0.f;

    auto stage = [&](int kt, int bi) {
        #pragma unroll
        for (int i = 0; i < 2; i++) {      // K tile: 32 rows x 16 chunks (swizzled src)
            int chunk = tid + i * 256;
            int r = chunk >> 4, c = chunk & 15;
            int cs = (c & 8) | ((c ^ r) & 7);
            gll16(QKb + (size_t)(b * S_LEN + kt * 32 + r) * 1024 + 512 + h * 128 + cs * 8,
                  (void*)(Ks[bi] + chunk * 8));
        }
        #pragma unroll
        for (int i = 0; i < 2; i++) {      // Vt tile: 128 rows x 4 chunks
            int chunk = tid + i * 256;
            int r = chunk >> 2, c = chunk & 3;
            int cs = (c ^ r) & 3;
            gll16(Vt + ((size_t)(b * 4 + h) * 128 + r) * S_LEN + kt * 32 + cs * 8,
                  (void*)(Vts[bi] + chunk * 8));
        }
    };

    stage(kt0, 0);
    int buf = 0;

    for (int t = 0; t < nkt; t++) {
        int kt = kt0 + t;
        if (t + 1 < nkt) {
            stage(kt + 1, buf ^ 1);   // prefetch; stays in flight across barriers
            asm volatile("s_waitcnt vmcnt(4)" ::: "memory");
        } else {
            asm volatile("s_waitcnt vmcnt(0)" ::: "memory");
        }
        __builtin_amdgcn_s_barrier();          // current tile ready (counted wait)
        // --- S^T = K Q^T (swapped): lane holds q-row c15, tokens c*16+g*4+r ---
        f32x4 sf[2];
        __builtin_amdgcn_s_setprio(1);
        #pragma unroll
        for (int c = 0; c < 2; c++) {
            sf[c] = (f32x4){0.f, 0.f, 0.f, 0.f};
            int tok16 = c * 16 + c15;
            #pragma unroll
            for (int k0 = 0; k0 < 4; k0++) {
                int ck = k0 * 4 + g;
                int cs = (ck & 8) | ((ck ^ tok16) & 7);
                bf16x8 kf = *(const bf16x8*)((const char*)Ks[buf] + tok16 * 256 + cs * 16);
                sf[c] = __builtin_amdgcn_mfma_f32_16x16x32_bf16(kf, q[k0], sf[c], 0, 0, 0);
            }
        }
        __builtin_amdgcn_s_setprio(0);
        // --- mask: last two tiles only (incl. PRE block) ---
        if (kt >= 2 * qb) {
            int qr = qb * 64 + w * 16 + c15;
            #pragma unroll
            for (int c = 0; c < 2; c++)
                #pragma unroll
                for (int r = 0; r < 4; r++) {
                    int tok = kt * 32 + c * 16 + g * 4 + r;
                    bool ok = (tok <= qr) || (qr < 20 && tok < 20);
                    if (!ok) sf[c][r] = -3e38f;
                }
        }
        // --- row max: in-lane tree + 2 shfl (raw score domain) ---
        float t0 = fmaxf(fmaxf(sf[0][0], sf[0][1]), fmaxf(sf[0][2], sf[0][3]));
        float t1 = fmaxf(fmaxf(sf[1][0], sf[1][1]), fmaxf(sf[1][2], sf[1][3]));
        float mt = fmaxf(t0, t1);
        mt = fmaxf(mt, __shfl_xor(mt, 16));
        mt = fmaxf(mt, __shfl_xor(mt, 32));
        // --- defer-max (T13): 8 nats = 90.5 raw ---
        bool need = !__all(mt <= m + 90.5f);
        float sc = 1.f;
        if (need) {
            float mn = fmaxf(m, mt);
            sc = __builtin_amdgcn_exp2f((m - mn) * SCL2);
            m = mn;
        }
        float msc2 = m * SCL2;
        #pragma unroll
        for (int c = 0; c < 2; c++)
            #pragma unroll
            for (int r = 0; r < 4; r++)
                sf[c][r] = __builtin_amdgcn_exp2f(fmaf(sf[c][r], SCL2, -msc2));
        float s0 = (sf[0][0] + sf[0][1]) + (sf[0][2] + sf[0][3]);
        float s1 = (sf[1][0] + sf[1][1]) + (sf[1][2] + sf[1][3]);
        float ls = s0 + s1;
        ls += __shfl_xor(ls, 16);
        ls += __shfl_xor(ls, 32);
        if (need) l *= sc;
        l += ls;
        // --- P -> Plds via v_cvt_pk_bf16_f32 (T12), packed b64 writes ---
        #pragma unroll
        for (int c = 0; c < 2; c++) {
            u32x2 pk = { cvtpk(sf[c][0], sf[c][1]), cvtpk(sf[c][2], sf[c][3]) };
            *(u32x2*)&Plds[w][c15 * 40 + c * 16 + g * 4] = pk;
        }
        // --- rescale O (skipped when deferred) ---
        if (need) {
            float r0 = __shfl(sc, g * 4 + 0);
            float r1 = __shfl(sc, g * 4 + 1);
            float r2 = __shfl(sc, g * 4 + 2);
            float r3 = __shfl(sc, g * 4 + 3);
            #pragma unroll
            for (int cd = 0; cd < 8; cd++) {
                o[cd][0] *= r0; o[cd][1] *= r1; o[cd][2] *= r2; o[cd][3] *= r3;
            }
        }
        // --- O += P V (single K=32 MFMA per d-group) ---
        bf16x8 pa = *(const bf16x8*)((const char*)&Plds[w][0] + c15 * 80 + g * 16);
        __builtin_amdgcn_s_setprio(1);
        #pragma unroll
        for (int cd = 0; cd < 8; cd++) {
            int dv = cd * 16 + c15;
            int cs = (g ^ dv) & 3;
            bf16x8 vf = *(const bf16x8*)((const char*)Vts[buf] + dv * 64 + cs * 16);
            o[cd] = __builtin_amdgcn_mfma_f32_16x16x32_bf16(pa, vf, o[cd], 0, 0, 0);
        }
        __builtin_amdgcn_s_setprio(0);
        __builtin_amdgcn_s_barrier();          // WAR: all waves done reading buf
        buf ^= 1;
    }

    if (split < 0) {
        float li0 = 1.f / __shfl(l, g * 4 + 0);
        float li1 = 1.f / __shfl(l, g * 4 + 1);
        float li2 = 1.f / __shfl(l, g * 4 + 2);
        float li3 = 1.f / __shfl(l, g * 4 + 3);
        size_t obase = (size_t)(b * S_LEN + qb * 64 + w * 16 + g * 4) * 512 + h * 128;
        #pragma unroll
        for (int cd = 0; cd < 8; cd++) {
            Ob[obase + 0 * 512 + cd * 16 + c15] = f2bf(o[cd][0] * li0);
            Ob[obase + 1 * 512 + cd * 16 + c15] = f2bf(o[cd][1] * li1);
            Ob[obase + 2 * 512 + cd * 16 + c15] = f2bf(o[cd][2] * li2);
            Ob[obase + 3 * 512 + cd * 16 + c15] = f2bf(o[cd][3] * li3);
        }
    } else {
        unsigned short* op = Opart + (size_t)split * 8192;
        int rb = w * 16 + g * 4;
        #pragma unroll
        for (int cd = 0; cd < 8; cd++) {
            op[(rb + 0) * 128 + cd * 16 + c15] = f2bf(o[cd][0]);
            op[(rb + 1) * 128 + cd * 16 + c15] = f2bf(o[cd][1]);
            op[(rb + 2) * 128 + cd * 16 + c15] = f2bf(o[cd][2]);
            op[(rb + 3) * 128 + cd * 16 + c15] = f2bf(o[cd][3]);
        }
        if (g == 0) {
            Mpart[split * 64 + w * 16 + c15] = m;
            Lpart[split * 64 + w * 16 + c15] = l;
        }
    }
}

// ---------------- merge split-K partials (qb 16..31) ----------------
__global__ __launch_bounds__(256) void attn_merge(
    const unsigned short* __restrict__ Opart,
    const float* __restrict__ Mpart, const float* __restrict__ Lpart,
    unsigned short* __restrict__ Ob)
{
    const float SCL2 = 0.12751742795f;
    int bid = blockIdx.x;                 // bh*16 + (qb-16)
    int bh = bid >> 4, qe = bid & 15;
    int qb = 16 + qe;
    int b = bh >> 2, h = bh & 3;
    int p0 = bh * 32 + qe * 2;
    int t = threadIdx.x;
    int r = t >> 2, dq = t & 3;
    float m0 = Mpart[p0 * 64 + r], m1 = Mpart[(p0 + 1) * 64 + r];
    float l0 = Lpart[p0 * 64 + r], l1 = Lpart[(p0 + 1) * 64 + r];
    float ms = fmaxf(m0, m1);
    float w0 = __builtin_amdgcn_exp2f((m0 - ms) * SCL2);
    float w1 = __builtin_amdgcn_exp2f((m1 - ms) * SCL2);
    float linv = 1.f / (l0 * w0 + l1 * w1);
    w0 *= linv; w1 *= linv;
    const unsigned short* o0 = Opart + (size_t)p0 * 8192 + r * 128 + dq * 32;
    const unsigned short* o1 = o0 + 8192;
    unsigned short* od = Ob + (size_t)(b * S_LEN + qb * 64 + r) * 512 + h * 128 + dq * 32;
    #pragma unroll
    for (int i = 0; i < 4; i++) {
        u16x8 a = *(const u16x8*)(o0 + i * 8);
        u16x8 c = *(const u16x8*)(o1 + i * 8);
        u16x8 d;
        #pragma unroll
        for (int j = 0; j < 8; j++)
            d[j] = f2bf(bf2f(a[j]) * w0 + bf2f(c[j]) * w1);
        *(u16x8*)(od + i * 8) = d;
    }
}

// ---------------- X = LayerNorm(X + D)*g + b ;  Xb = bf16(X) ----------------
// Wave-per-row: 4 rows/block, vectorized 16B loads, pure shfl reduce.
__global__ __launch_bounds__(256) void add_ln_kernel(
    float* __restrict__ X, const unsigned short* __restrict__ D,
    const float* __restrict__ gw, const float* __restrict__ bw,
    unsigned short* __restrict__ Xb)
{
    int wv = threadIdx.x >> 6, lane = threadIdx.x & 63;
    int row = blockIdx.x * 4 + wv;
    size_t base = (size_t)row * DMODEL + lane * 8;
    float4 x0 = *(const float4*)(X + base);
    float4 x1 = *(const float4*)(X + base + 4);
    u16x8 d8 = *(const u16x8*)(D + base);
    float v[8];
    v[0] = x0.x + bf2f(d8[0]); v[1] = x0.y + bf2f(d8[1]);
    v[2] = x0.z + bf2f(d8[2]); v[3] = x0.w + bf2f(d8[3]);
    v[4] = x1.x + bf2f(d8[4]); v[5] = x1.y + bf2f(d8[5]);
    v[6] = x1.z + bf2f(d8[6]); v[7] = x1.w + bf2f(d8[7]);
    float s = 0.f, sq = 0.f;
    #pragma unroll
    for (int i = 0; i < 8; i++) { s += v[i]; sq = fmaf(v[i], v[i], sq); }
    #pragma unroll
    for (int off = 32; off > 0; off >>= 1) {
        s  += __shfl_xor(s, off);
        sq += __shfl_xor(sq, off);
    }
    float mu = s * (1.f / DMODEL);
    float var = sq * (1.f / DMODEL) - mu * mu;
    float rs = rsqrtf(var + 1e-5f);
    float4 g0 = *(const float4*)(gw + lane * 8);
    float4 g1 = *(const float4*)(gw + lane * 8 + 4);
    float4 b0 = *(const float4*)(bw + lane * 8);
    float4 b1 = *(const float4*)(bw + lane * 8 + 4);
    float y[8];
    y[0] = (v[0] - mu) * rs * g0.x + b0.x; y[1] = (v[1] - mu) * rs * g0.y + b0.y;
    y[2] = (v[2] - mu) * rs * g0.z + b0.z; y[3] = (v[3] - mu) * rs * g0.w + b0.w;
    y[4] = (v[4] - mu) * rs * g1.x + b1.x; y[5] = (v[5] - mu) * rs * g1.y + b1.y;
    y[6] = (v[6] - mu) * rs * g1.z + b1.z; y[7] = (v[7] - mu) * rs * g1.w + b1.w;
    float4 o0 = { y[0], y[1], y[2], y[3] };
    float4 o1 = { y[4], y[5], y[6], y[7] };
    *(float4*)(X + base) = o0;
    *(float4*)(X + base + 4) = o1;
    u16x8 ob;
    #pragma unroll
    for (int i = 0; i < 8; i++) ob[i] = f2bf(y[i]);
    *(u16x8*)(Xb + base) = ob;
}

// ---------------- out = tanh(X @ dec_w^T + dec_b) * 10 ----------------
__global__ __launch_bounds__(256) void decoder_kernel(
    const float* __restrict__ X, const float* __restrict__ w,
    const float* __restrict__ bias, float* __restrict__ out)
{
    int tid = threadIdx.x;
    int lane = tid & 63;
    int row = blockIdx.x * 4 + (tid >> 6);
    float s = 0.f;
    size_t base = (size_t)row * DMODEL;
    #pragma unroll
    for (int i = 0; i < 8; i++) s = fmaf(X[base + lane + i * 64], w[lane + i * 64], s);
    #pragma unroll
    for (int off = 32; off > 0; off >>= 1) s += __shfl_down(s, off);
    if (lane == 0) out[row] = tanhf(s + bias[0]) * 10.0f;
}

extern "C" void kernel_launch(void* const* d_in, const int* in_sizes, int n_in,
                              void* d_out, int out_size, void* d_ws, size_t ws_size,
                              hipStream_t stream)
{
    const float* src   = (const float*)d_in[0];
    const float* emb_w = (const float*)d_in[1];
    const float* emb_b = (const float*)d_in[2];
    const float* in_w  = (const float*)d_in[3];
    const float* in_b  = (const float*)d_in[4];
    const float* out_w = (const float*)d_in[5];
    const float* out_b = (const float*)d_in[6];
    const float* ln1_g = (const float*)d_in[7];
    const float* ln1_b = (const float*)d_in[8];
    const float* ln2_g = (const float*)d_in[9];
    const float* ln2_b = (const float*)d_in[10];
    const float* ff1_w = (const float*)d_in[11];
    const float* ff1_b = (const float*)d_in[12];
    const float* ff2_w = (const float*)d_in[13];
    const float* ff2_b = (const float*)d_in[14];
    const float* dec_w = (const float*)d_in[15];
    const float* dec_b = (const float*)d_in[16];

    char* ws = (char*)d_ws;
    float*          X   = (float*)ws;                              // 16 MB
    unsigned short* Xb  = (unsigned short*)(ws + (16u << 20));     //  8 MB
    unsigned short* Pb  = (unsigned short*)(ws + (24u << 20));     //  8 MB
    unsigned short* Ob  = (unsigned short*)(ws + (32u << 20));     //  8 MB
    unsigned short* QKb = (unsigned short*)(ws + (40u << 20));     // 16 MB
    unsigned short* Vt  = (unsigned short*)(ws + (56u << 20));     //  8 MB
    unsigned short* Hb  = (unsigned short*)(ws + (40u << 20));     // 32 MB (overlaps QKb+Vt)
    // Attention split-K partials overlay regions that are DEAD during
    // flash+merge: Opart over Xb (rewritten by add_ln before next read),
    // Mpart/Lpart over Pb (written by O-proj after merge).
    unsigned short* Opart = (unsigned short*)(ws + (16u << 20));   // 512*8192 bf16 = 8 MB
    float* Mpart = (float*)(ws + (24u << 20));                     // 512*64 f32
    float* Lpart = Mpart + 512 * 64;
    unsigned short* in_wb  = (unsigned short*)(ws + (72u << 20));
    unsigned short* out_wb = in_wb  + 3u * 1536 * 512;
    unsigned short* ff1_wb = out_wb + 3u * 512 * 512;
    unsigned short* ff2_wb = ff1_wb + 3u * 2048 * 512;
    float* outp = (float*)d_out;
    const int M = 4 * S_LEN;   // 8192

    conv_all<<<9216, 256, 0, stream>>>(
        (const float4*)in_w, (const float4*)out_w,
        (const float4*)ff1_w, (const float4*)ff2_w,
        (u16x4*)in_wb, (u16x4*)out_wb, (u16x4*)ff1_wb, (u16x4*)ff2_wb);

    embed_kernel<<<M, 256, 0, stream>>>(src, emb_w, emb_b, X, Xb);

    for (int l = 0; l < 3; l++) {
        gemm_bf16<3, 128><<<dim3(768), 256, 0, stream>>>(
            Xb, 512, in_wb + (size_t)l * 1536 * 512, 512, in_b + l * 1536,
            QKb, 1024, Vt, 12);
        flash_attn<<<768, 256, 0, stream>>>(QKb, Vt, Ob, Opart, Mpart, Lpart);
        attn_merge<<<256, 256, 0, stream>>>(Opart, Mpart, Lpart, Ob);
        gemm_bf16<1, 64><<<dim3(512), 256, 0, stream>>>(
            Ob, 512, out_wb + (size_t)l * 512 * 512, 512, out_b + l * 512,
            Pb, 512, nullptr, 8);
        add_ln_kernel<<<M / 4, 256, 0, stream>>>(X, Pb, ln1_g + l * 512, ln1_b + l * 512, Xb);
        gemm_bf16<2, 128><<<dim3(1024), 256, 0, stream>>>(
            Xb, 512, ff1_wb + (size_t)l * 2048 * 512, 512, ff1_b + l * 2048,
            Hb, 2048, nullptr, 16);
        gemm_bf16<1, 64><<<dim3(512), 256, 0, stream>>>(
            Hb, 2048, ff2_wb + (size_t)l * 512 * 2048, 2048, ff2_b + l * 512,
            Pb, 512, nullptr, 8);
        add_ln_kernel<<<M / 4, 256, 0, stream>>>(X, Pb, ln2_g + l * 512, ln2_b + l * 512, Xb);
    }

    decoder_kernel<<<M / 4, 256, 0, stream>>>(X, dec_w, dec_b, outp);
}

// Round 15
// 490.419 us; speedup vs baseline: 1.1312x; 1.0135x over previous
//
#include <hip/hip_runtime.h>

#define S_LEN 2048
#define DMODEL 512

typedef __attribute__((ext_vector_type(8))) short bf16x8;
typedef __attribute__((ext_vector_type(4))) float f32x4;
typedef __attribute__((ext_vector_type(4))) unsigned short u16x4;
typedef __attribute__((ext_vector_type(8))) unsigned short u16x8;
typedef __attribute__((ext_vector_type(2))) unsigned int u32x2;

__device__ __forceinline__ unsigned short f2bf(float f) {
    unsigned int u = __float_as_uint(f);
    u += 0x7fff + ((u >> 16) & 1);            // RNE
    return (unsigned short)(u >> 16);
}
__device__ __forceinline__ float bf2f(unsigned short h) {
    return __uint_as_float(((unsigned int)h) << 16);
}
__device__ __forceinline__ unsigned int cvtpk(float lo, float hi) {
    unsigned int r;
    asm("v_cvt_pk_bf16_f32 %0, %1, %2" : "=v"(r) : "v"(lo), "v"(hi));
    return r;
}
__device__ __forceinline__ void gll16(const void* g, void* l) {
    __builtin_amdgcn_global_load_lds(
        (const __attribute__((address_space(1))) unsigned int*)g,
        (__attribute__((address_space(3))) unsigned int*)l, 16, 0, 0);
}

// ---------------- fp32 -> bf16 bulk convert (all 4 weight tensors, 1 launch) ----------------
__global__ __launch_bounds__(256) void conv_all(
    const float4* __restrict__ in_w, const float4* __restrict__ out_w,
    const float4* __restrict__ ff1_w, const float4* __restrict__ ff2_w,
    u16x4* __restrict__ in_wb, u16x4* __restrict__ out_wb,
    u16x4* __restrict__ ff1_wb, u16x4* __restrict__ ff2_wb)
{
    int i = blockIdx.x * 256 + threadIdx.x;
    const float4* src; u16x4* dst; int j;
    if (i < 589824)        { src = in_w;  dst = in_wb;  j = i; }
    else if (i < 786432)   { src = out_w; dst = out_wb; j = i - 589824; }
    else if (i < 1572864)  { src = ff1_w; dst = ff1_wb; j = i - 786432; }
    else                   { src = ff2_w; dst = ff2_wb; j = i - 1572864; }
    float4 v = src[j];
    u16x4 o = { f2bf(v.x), f2bf(v.y), f2bf(v.z), f2bf(v.w) };
    dst[j] = o;
}

// ---------------- embedding + positional encoding ----------------
__global__ __launch_bounds__(256) void embed_kernel(
    const float* __restrict__ src, const float* __restrict__ ew,
    const float* __restrict__ eb, float* __restrict__ X,
    unsigned short* __restrict__ Xb)
{
    int rid = blockIdx.x;              // b*S + s
    int s = rid & (S_LEN - 1);
    int tid = threadIdx.x;
    __shared__ float sr[25];
    if (tid < 25) sr[tid] = src[rid * 25 + tid];
    __syncthreads();
    #pragma unroll
    for (int rep = 0; rep < 2; rep++) {
        int d = tid + rep * 256;
        float a = eb[d];
        #pragma unroll
        for (int k = 0; k < 25; k++) a = fmaf(sr[k], ew[d * 25 + k], a);
        int i2 = d & ~1;
        float div = expf(-(float)i2 * (9.210340371976184f / 512.f));
        float ang = (float)s * div;
        a += (d & 1) ? cosf(ang) : sinf(ang);
        X[(size_t)rid * DMODEL + d] = a;
        Xb[(size_t)rid * DMODEL + d] = f2bf(a);
    }
}

// ---------------- bf16 MFMA GEMM: C = A @ W^T + bias ----------------
// Double-buffered LDS pipeline with COUNTED vmcnt (T4): prefetch loads stay
// in flight across raw barriers (never drained to 0 in the main loop).
template<int MODE, int BN>
__global__ __launch_bounds__(256) void gemm_bf16(
    const unsigned short* __restrict__ A, int lda,
    const unsigned short* __restrict__ W, int K,
    const float* __restrict__ bias,
    unsigned short* __restrict__ out, int ldc,
    unsigned short* __restrict__ out2, int nbn)
{
    constexpr int NJ = BN / 32;
    constexpr int WC = BN / 2;                 // wave output cols
    __shared__ __align__(16) unsigned short LdsBuf[2][(128 + BN) * 64];
    int tid = threadIdx.x;
    int lane = tid & 63, w = tid >> 6;
    int g = lane >> 4, c15 = lane & 15;
    int wm = w >> 1, wn = w & 1;
    int bm, bn;
    if (BN == 64) {
        int raw = blockIdx.x;
        int lid = ((raw & 7) << 6) | (raw >> 3);  // consecutive lid -> same XCD
        bn = lid & 7; bm = lid >> 3;
    } else {
        int raw = blockIdx.x;
        int per = gridDim.x >> 3;                 // blocks per XCD chunk
        int lid = (raw & 7) * per + (raw >> 3);   // consecutive lid -> same XCD
        bn = lid % nbn; bm = lid / nbn;           // bn fastest: share A panel
    }

    f32x4 acc[4][NJ];
    #pragma unroll
    for (int i = 0; i < 4; i++)
        #pragma unroll
        for (int j = 0; j < NJ; j++) acc[i][j] = (f32x4){0.f, 0.f, 0.f, 0.f};

    auto stage = [&](int kk, int bi) {
        #pragma unroll
        for (int i = 0; i < 4; i++) {
            int chunk = tid + i * 256;
            int r = chunk >> 3, c = chunk & 7;
            int cs = c ^ (r & 7);
            gll16(A + (size_t)(bm * 128 + r) * lda + kk * 64 + cs * 8,
                  (void*)(LdsBuf[bi] + chunk * 8));
        }
        #pragma unroll
        for (int i = 0; i < BN / 32; i++) {
            int chunk = tid + i * 256;
            int r = chunk >> 3, c = chunk & 7;
            int cs = c ^ (r & 7);
            gll16(W + (size_t)(bn * BN + r) * K + kk * 64 + cs * 8,
                  (void*)(LdsBuf[bi] + 128 * 64 + chunk * 8));
        }
    };

    const int nk = K >> 6;
    stage(0, 0);
    int buf = 0;

    for (int kk = 0; kk < nk; kk++) {
        if (kk + 1 < nk) {
            stage(kk + 1, buf ^ 1);   // prefetch; stays in flight across barriers
            if constexpr (BN == 128) asm volatile("s_waitcnt vmcnt(8)" ::: "memory");
            else                     asm volatile("s_waitcnt vmcnt(6)" ::: "memory");
        } else {
            asm volatile("s_waitcnt vmcnt(0)" ::: "memory");
        }
        __builtin_amdgcn_s_barrier();          // current tile ready (counted wait)
        bf16x8 a[4][2], b[NJ][2];
        #pragma unroll
        for (int mi = 0; mi < 4; mi++) {
            int row = wm * 64 + mi * 16 + c15;
            #pragma unroll
            for (int h = 0; h < 2; h++) {
                int ck = (h * 4 + g) ^ (row & 7);
                a[mi][h] = *(const bf16x8*)((const char*)LdsBuf[buf] + row * 128 + ck * 16);
            }
        }
        #pragma unroll
        for (int nj = 0; nj < NJ; nj++) {
            int row = wn * WC + nj * 16 + c15;
            #pragma unroll
            for (int h = 0; h < 2; h++) {
                int ck = (h * 4 + g) ^ (row & 7);
                b[nj][h] = *(const bf16x8*)((const char*)(LdsBuf[buf] + 128 * 64)
                                            + row * 128 + ck * 16);
            }
        }
        __builtin_amdgcn_s_setprio(1);
        #pragma unroll
        for (int h = 0; h < 2; h++)
            #pragma unroll
            for (int mi = 0; mi < 4; mi++)
                #pragma unroll
                for (int nj = 0; nj < NJ; nj++)
                    acc[mi][nj] = __builtin_amdgcn_mfma_f32_16x16x32_bf16(
                        a[mi][h], b[nj][h], acc[mi][nj], 0, 0, 0);
        __builtin_amdgcn_s_setprio(0);
        __builtin_amdgcn_s_barrier();          // WAR: all waves done reading buf
        buf ^= 1;
    }
    __syncthreads();   // full sync before scratch overlays staging LDS

    // ---- per-wave LDS-transpose epilogue (staging LDS is dead past here) ----
    unsigned short* scr = (unsigned short*)LdsBuf + (size_t)w * 4608;  // [64][72]
    int colb0 = bn * BN + wn * WC;
    int rowb0 = bm * 128 + wm * 64;
    bool vout = (MODE == 3) && (colb0 >= 1024);
    #pragma unroll
    for (int nj = 0; nj < NJ; nj++) {
        float bv = bias[colb0 + nj * 16 + c15];
        #pragma unroll
        for (int mi = 0; mi < 4; mi++) {
            #pragma unroll
            for (int r = 0; r < 4; r++) {
                float v = acc[mi][nj][r] + bv;
                if (MODE == 2) v = fmaxf(v, 0.f);
                int rl = mi * 16 + g * 4 + r;
                int cl = nj * 16 + c15;
                if (!vout) scr[rl * 72 + cl] = f2bf(v);
                else       scr[cl * 72 + rl] = f2bf(v);   // transposed for V
            }
        }
    }
    // per-wave scratch: no barrier needed (compiler waits lgkmcnt on reads)
    constexpr int NP = WC / 8;        // 8 passes (BN=128) or 4 (BN=64)
    if (!vout) {
        #pragma unroll
        for (int p = 0; p < NP; p++) {
            int idx = p * 64 + lane;
            int row = idx / (WC / 8);
            int cc  = (idx % (WC / 8)) * 8;
            u16x8 v = *(const u16x8*)(scr + row * 72 + cc);
            *(u16x8*)(out + (size_t)(rowb0 + row) * ldc + colb0 + cc) = v;
        }
    } else {
        int cv0 = colb0 - 1024;                   // multiple of 64
        int hh = cv0 >> 7, d0 = cv0 & 127;
        int bb = rowb0 >> 11, t0 = rowb0 & (S_LEN - 1);
        unsigned short* vbase = out2 + ((size_t)(bb * 4 + hh) * 128 + d0) * S_LEN + t0;
        #pragma unroll
        for (int p = 0; p < 8; p++) {
            int idx = p * 64 + lane;
            int rd = idx >> 3;                    // d offset 0..63
            int tc = (idx & 7) * 8;               // t offset
            u16x8 v = *(const u16x8*)(scr + rd * 72 + tc);
            *(u16x8*)(vbase + (size_t)rd * S_LEN + tc) = v;
        }
    }
}

// ---------------- bf16 MFMA flash attention ----------------
// KVBLK=32, split-K for qb>=16, counted-vmcnt double-buffer staging,
// exp2-domain softmax + v_cvt_pk P-pack, LPT dispatch order (longest
// blocks first -> tail filled by short blocks).
__global__ __launch_bounds__(256) void flash_attn(
    const unsigned short* __restrict__ QKb,
    const unsigned short* __restrict__ Vt,
    unsigned short* __restrict__ Ob,
    unsigned short* __restrict__ Opart,   // [512][64*128] bf16
    float* __restrict__ Mpart,            // [512][64]
    float* __restrict__ Lpart)            // [512][64]
{
    __shared__ __align__(16) unsigned short Ks[2][32 * 128];
    __shared__ __align__(16) unsigned short Vts[2][128 * 32];
    __shared__ __align__(16) unsigned short Plds[4][16 * 40];   // stride 40 u16
    const float SCL2 = 0.12751742795f;    // (1/sqrt(128)) * log2(e)
    // LPT work table: entry = qb*4 + type (0=direct, 1=split j0, 2=split j1),
    // sorted by descending tile count (direct: 2qb+2, split: qb+1).
    static const unsigned char wtab[48] = {
        60, 125,126, 121,122,  56, 117,118, 113,114,
        52, 109,110, 105,106,  48, 101,102,  97, 98,
        44,  93, 94,  89, 90,  40,  85, 86,  81, 82,
        36,  77, 78,  73, 74,  32,  69, 70,  65, 66,
        28,  24,  20,  16,  12,   8,   4,   0
    };
    int tid = threadIdx.x;
    int lane = tid & 63, w = tid >> 6;
    int g = lane >> 4, c15 = lane & 15;
    int raw = blockIdx.x;
    int lid = (raw & 7) * 96 + (raw >> 3);       // XCD-chunked (768 = 8*96)
    int bh = lid / 48, idx = lid - bh * 48;
    int b = bh >> 2, h = bh & 3;
    int v = wtab[idx];
    int qb = v >> 2, ty = v & 3;
    int qbkt0, nkt, split;
    if (ty == 0) { qbkt0 = 0; nkt = 2 * qb + 2; split = -1; }
    else {
        int j = ty - 1;
        qbkt0 = j * (qb + 1);
        nkt = qb + 1;
        split = bh * 32 + (qb - 16) * 2 + j;
    }
    const int kt0 = qbkt0;

    // Q fragments (B-operand): this lane's q-row = qb*64 + w*16 + c15
    bf16x8 q[4];
    {
        const unsigned short* qrow =
            QKb + (size_t)(b * S_LEN + qb * 64 + w * 16 + c15) * 1024 + h * 128;
        #pragma unroll
        for (int k0 = 0; k0 < 4; k0++) q[k0] = *(const bf16x8*)(qrow + k0 * 32 + g * 8);
    }
    f32x4 o[8];
    #pragma unroll
    for (int cd = 0; cd < 8; cd++) o[cd] = (f32x4){0.f, 0.f, 0.f, 0.f};
    float m = -3e38f, l = 0.f;

    auto stage = [&](int kt, int bi) {
        #pragma unroll
        for (int i = 0; i < 2; i++) {      // K tile: 32 rows x 16 chunks (swizzled src)
            int chunk = tid + i * 256;
            int r = chunk >> 4, c = chunk & 15;
            int cs = (c & 8) | ((c ^ r) & 7);
            gll16(QKb + (size_t)(b * S_LEN + kt * 32 + r) * 1024 + 512 + h * 128 + cs * 8,
                  (void*)(Ks[bi] + chunk * 8));
        }
        #pragma unroll
        for (int i = 0; i < 2; i++) {      // Vt tile: 128 rows x 4 chunks
            int chunk = tid + i * 256;
            int r = chunk >> 2, c = chunk & 3;
            int cs = (c ^ r) & 3;
            gll16(Vt + ((size_t)(b * 4 + h) * 128 + r) * S_LEN + kt * 32 + cs * 8,
                  (void*)(Vts[bi] + chunk * 8));
        }
    };

    stage(kt0, 0);
    int buf = 0;

    for (int t = 0; t < nkt; t++) {
        int kt = kt0 + t;
        if (t + 1 < nkt) {
            stage(kt + 1, buf ^ 1);   // prefetch; stays in flight across barriers
            asm volatile("s_waitcnt vmcnt(4)" ::: "memory");
        } else {
            asm volatile("s_waitcnt vmcnt(0)" ::: "memory");
        }
        __builtin_amdgcn_s_barrier();          // current tile ready (counted wait)
        // --- S^T = K Q^T (swapped): lane holds q-row c15, tokens c*16+g*4+r ---
        f32x4 sf[2];
        __builtin_amdgcn_s_setprio(1);
        #pragma unroll
        for (int c = 0; c < 2; c++) {
            sf[c] = (f32x4){0.f, 0.f, 0.f, 0.f};
            int tok16 = c * 16 + c15;
            #pragma unroll
            for (int k0 = 0; k0 < 4; k0++) {
                int ck = k0 * 4 + g;
                int cs = (ck & 8) | ((ck ^ tok16) & 7);
                bf16x8 kf = *(const bf16x8*)((const char*)Ks[buf] + tok16 * 256 + cs * 16);
                sf[c] = __builtin_amdgcn_mfma_f32_16x16x32_bf16(kf, q[k0], sf[c], 0, 0, 0);
            }
        }
        __builtin_amdgcn_s_setprio(0);
        // --- mask: last two tiles only (incl. PRE block) ---
        if (kt >= 2 * qb) {
            int qr = qb * 64 + w * 16 + c15;
            #pragma unroll
            for (int c = 0; c < 2; c++)
                #pragma unroll
                for (int r = 0; r < 4; r++) {
                    int tok = kt * 32 + c * 16 + g * 4 + r;
                    bool ok = (tok <= qr) || (qr < 20 && tok < 20);
                    if (!ok) sf[c][r] = -3e38f;
                }
        }
        // --- row max: in-lane tree + 2 shfl (raw score domain) ---
        float t0 = fmaxf(fmaxf(sf[0][0], sf[0][1]), fmaxf(sf[0][2], sf[0][3]));
        float t1 = fmaxf(fmaxf(sf[1][0], sf[1][1]), fmaxf(sf[1][2], sf[1][3]));
        float mt = fmaxf(t0, t1);
        mt = fmaxf(mt, __shfl_xor(mt, 16));
        mt = fmaxf(mt, __shfl_xor(mt, 32));
        // --- defer-max (T13): 8 nats = 90.5 raw ---
        bool need = !__all(mt <= m + 90.5f);
        float sc = 1.f;
        if (need) {
            float mn = fmaxf(m, mt);
            sc = __builtin_amdgcn_exp2f((m - mn) * SCL2);
            m = mn;
        }
        float msc2 = m * SCL2;
        #pragma unroll
        for (int c = 0; c < 2; c++)
            #pragma unroll
            for (int r = 0; r < 4; r++)
                sf[c][r] = __builtin_amdgcn_exp2f(fmaf(sf[c][r], SCL2, -msc2));
        float s0 = (sf[0][0] + sf[0][1]) + (sf[0][2] + sf[0][3]);
        float s1 = (sf[1][0] + sf[1][1]) + (sf[1][2] + sf[1][3]);
        float ls = s0 + s1;
        ls += __shfl_xor(ls, 16);
        ls += __shfl_xor(ls, 32);
        if (need) l *= sc;
        l += ls;
        // --- P -> Plds via v_cvt_pk_bf16_f32 (T12), packed b64 writes ---
        #pragma unroll
        for (int c = 0; c < 2; c++) {
            u32x2 pk = { cvtpk(sf[c][0], sf[c][1]), cvtpk(sf[c][2], sf[c][3]) };
            *(u32x2*)&Plds[w][c15 * 40 + c * 16 + g * 4] = pk;
        }
        // --- rescale O (skipped when deferred) ---
        if (need) {
            float r0 = __shfl(sc, g * 4 + 0);
            float r1 = __shfl(sc, g * 4 + 1);
            float r2 = __shfl(sc, g * 4 + 2);
            float r3 = __shfl(sc, g * 4 + 3);
            #pragma unroll
            for (int cd = 0; cd < 8; cd++) {
                o[cd][0] *= r0; o[cd][1] *= r1; o[cd][2] *= r2; o[cd][3] *= r3;
            }
        }
        // --- O += P V (single K=32 MFMA per d-group) ---
        bf16x8 pa = *(const bf16x8*)((const char*)&Plds[w][0] + c15 * 80 + g * 16);
        __builtin_amdgcn_s_setprio(1);
        #pragma unroll
        for (int cd = 0; cd < 8; cd++) {
            int dv = cd * 16 + c15;
            int cs = (g ^ dv) & 3;
            bf16x8 vf = *(const bf16x8*)((const char*)Vts[buf] + dv * 64 + cs * 16);
            o[cd] = __builtin_amdgcn_mfma_f32_16x16x32_bf16(pa, vf, o[cd], 0, 0, 0);
        }
        __builtin_amdgcn_s_setprio(0);
        __builtin_amdgcn_s_barrier();          // WAR: all waves done reading buf
        buf ^= 1;
    }

    if (split < 0) {
        float li0 = 1.f / __shfl(l, g * 4 + 0);
        float li1 = 1.f / __shfl(l, g * 4 + 1);
        float li2 = 1.f / __shfl(l, g * 4 + 2);
        float li3 = 1.f / __shfl(l, g * 4 + 3);
        size_t obase = (size_t)(b * S_LEN + qb * 64 + w * 16 + g * 4) * 512 + h * 128;
        #pragma unroll
        for (int cd = 0; cd < 8; cd++) {
            Ob[obase + 0 * 512 + cd * 16 + c15] = f2bf(o[cd][0] * li0);
            Ob[obase + 1 * 512 + cd * 16 + c15] = f2bf(o[cd][1] * li1);
            Ob[obase + 2 * 512 + cd * 16 + c15] = f2bf(o[cd][2] * li2);
            Ob[obase + 3 * 512 + cd * 16 + c15] = f2bf(o[cd][3] * li3);
        }
    } else {
        unsigned short* op = Opart + (size_t)split * 8192;
        int rb = w * 16 + g * 4;
        #pragma unroll
        for (int cd = 0; cd < 8; cd++) {
            op[(rb + 0) * 128 + cd * 16 + c15] = f2bf(o[cd][0]);
            op[(rb + 1) * 128 + cd * 16 + c15] = f2bf(o[cd][1]);
            op[(rb + 2) * 128 + cd * 16 + c15] = f2bf(o[cd][2]);
            op[(rb + 3) * 128 + cd * 16 + c15] = f2bf(o[cd][3]);
        }
        if (g == 0) {
            Mpart[split * 64 + w * 16 + c15] = m;
            Lpart[split * 64 + w * 16 + c15] = l;
        }
    }
}

// ---------------- merge split-K partials (qb 16..31) ----------------
__global__ __launch_bounds__(256) void attn_merge(
    const unsigned short* __restrict__ Opart,
    const float* __restrict__ Mpart, const float* __restrict__ Lpart,
    unsigned short* __restrict__ Ob)
{
    const float SCL2 = 0.12751742795f;
    int bid = blockIdx.x;                 // bh*16 + (qb-16)
    int bh = bid >> 4, qe = bid & 15;
    int qb = 16 + qe;
    int b = bh >> 2, h = bh & 3;
    int p0 = bh * 32 + qe * 2;
    int t = threadIdx.x;
    int r = t >> 2, dq = t & 3;
    float m0 = Mpart[p0 * 64 + r], m1 = Mpart[(p0 + 1) * 64 + r];
    float l0 = Lpart[p0 * 64 + r], l1 = Lpart[(p0 + 1) * 64 + r];
    float ms = fmaxf(m0, m1);
    float w0 = __builtin_amdgcn_exp2f((m0 - ms) * SCL2);
    float w1 = __builtin_amdgcn_exp2f((m1 - ms) * SCL2);
    float linv = 1.f / (l0 * w0 + l1 * w1);
    w0 *= linv; w1 *= linv;
    const unsigned short* o0 = Opart + (size_t)p0 * 8192 + r * 128 + dq * 32;
    const unsigned short* o1 = o0 + 8192;
    unsigned short* od = Ob + (size_t)(b * S_LEN + qb * 64 + r) * 512 + h * 128 + dq * 32;
    #pragma unroll
    for (int i = 0; i < 4; i++) {
        u16x8 a = *(const u16x8*)(o0 + i * 8);
        u16x8 c = *(const u16x8*)(o1 + i * 8);
        u16x8 d;
        #pragma unroll
        for (int j = 0; j < 8; j++)
            d[j] = f2bf(bf2f(a[j]) * w0 + bf2f(c[j]) * w1);
        *(u16x8*)(od + i * 8) = d;
    }
}

// ---------------- X = LayerNorm(X + D)*g + b ;  Xb = bf16(X) ----------------
// Wave-per-row: 4 rows/block, vectorized 16B loads, pure shfl reduce.
__global__ __launch_bounds__(256) void add_ln_kernel(
    float* __restrict__ X, const unsigned short* __restrict__ D,
    const float* __restrict__ gw, const float* __restrict__ bw,
    unsigned short* __restrict__ Xb)
{
    int wv = threadIdx.x >> 6, lane = threadIdx.x & 63;
    int row = blockIdx.x * 4 + wv;
    size_t base = (size_t)row * DMODEL + lane * 8;
    float4 x0 = *(const float4*)(X + base);
    float4 x1 = *(const float4*)(X + base + 4);
    u16x8 d8 = *(const u16x8*)(D + base);
    float v[8];
    v[0] = x0.x + bf2f(d8[0]); v[1] = x0.y + bf2f(d8[1]);
    v[2] = x0.z + bf2f(d8[2]); v[3] = x0.w + bf2f(d8[3]);
    v[4] = x1.x + bf2f(d8[4]); v[5] = x1.y + bf2f(d8[5]);
    v[6] = x1.z + bf2f(d8[6]); v[7] = x1.w + bf2f(d8[7]);
    float s = 0.f, sq = 0.f;
    #pragma unroll
    for (int i = 0; i < 8; i++) { s += v[i]; sq = fmaf(v[i], v[i], sq); }
    #pragma unroll
    for (int off = 32; off > 0; off >>= 1) {
        s  += __shfl_xor(s, off);
        sq += __shfl_xor(sq, off);
    }
    float mu = s * (1.f / DMODEL);
    float var = sq * (1.f / DMODEL) - mu * mu;
    float rs = rsqrtf(var + 1e-5f);
    float4 g0 = *(const float4*)(gw + lane * 8);
    float4 g1 = *(const float4*)(gw + lane * 8 + 4);
    float4 b0 = *(const float4*)(bw + lane * 8);
    float4 b1 = *(const float4*)(bw + lane * 8 + 4);
    float y[8];
    y[0] = (v[0] - mu) * rs * g0.x + b0.x; y[1] = (v[1] - mu) * rs * g0.y + b0.y;
    y[2] = (v[2] - mu) * rs * g0.z + b0.z; y[3] = (v[3] - mu) * rs * g0.w + b0.w;
    y[4] = (v[4] - mu) * rs * g1.x + b1.x; y[5] = (v[5] - mu) * rs * g1.y + b1.y;
    y[6] = (v[6] - mu) * rs * g1.z + b1.z; y[7] = (v[7] - mu) * rs * g1.w + b1.w;
    float4 o0 = { y[0], y[1], y[2], y[3] };
    float4 o1 = { y[4], y[5], y[6], y[7] };
    *(float4*)(X + base) = o0;
    *(float4*)(X + base + 4) = o1;
    u16x8 ob;
    #pragma unroll
    for (int i = 0; i < 8; i++) ob[i] = f2bf(y[i]);
    *(u16x8*)(Xb + base) = ob;
}

// ---------------- out = tanh(X @ dec_w^T + dec_b) * 10 ----------------
__global__ __launch_bounds__(256) void decoder_kernel(
    const float* __restrict__ X, const float* __restrict__ w,
    const float* __restrict__ bias, float* __restrict__ out)
{
    int tid = threadIdx.x;
    int lane = tid & 63;
    int row = blockIdx.x * 4 + (tid >> 6);
    float s = 0.f;
    size_t base = (size_t)row * DMODEL;
    #pragma unroll
    for (int i = 0; i < 8; i++) s = fmaf(X[base + lane + i * 64], w[lane + i * 64], s);
    #pragma unroll
    for (int off = 32; off > 0; off >>= 1) s += __shfl_down(s, off);
    if (lane == 0) out[row] = tanhf(s + bias[0]) * 10.0f;
}

extern "C" void kernel_launch(void* const* d_in, const int* in_sizes, int n_in,
                              void* d_out, int out_size, void* d_ws, size_t ws_size,
                              hipStream_t stream)
{
    const float* src   = (const float*)d_in[0];
    const float* emb_w = (const float*)d_in[1];
    const float* emb_b = (const float*)d_in[2];
    const float* in_w  = (const float*)d_in[3];
    const float* in_b  = (const float*)d_in[4];
    const float* out_w = (const float*)d_in[5];
    const float* out_b = (const float*)d_in[6];
    const float* ln1_g = (const float*)d_in[7];
    const float* ln1_b = (const float*)d_in[8];
    const float* ln2_g = (const float*)d_in[9];
    const float* ln2_b = (const float*)d_in[10];
    const float* ff1_w = (const float*)d_in[11];
    const float* ff1_b = (const float*)d_in[12];
    const float* ff2_w = (const float*)d_in[13];
    const float* ff2_b = (const float*)d_in[14];
    const float* dec_w = (const float*)d_in[15];
    const float* dec_b = (const float*)d_in[16];

    char* ws = (char*)d_ws;
    float*          X   = (float*)ws;                              // 16 MB
    unsigned short* Xb  = (unsigned short*)(ws + (16u << 20));     //  8 MB
    unsigned short* Pb  = (unsigned short*)(ws + (24u << 20));     //  8 MB
    unsigned short* Ob  = (unsigned short*)(ws + (32u << 20));     //  8 MB
    unsigned short* QKb = (unsigned short*)(ws + (40u << 20));     // 16 MB
    unsigned short* Vt  = (unsigned short*)(ws + (56u << 20));     //  8 MB
    unsigned short* Hb  = (unsigned short*)(ws + (40u << 20));     // 32 MB (overlaps QKb+Vt)
    // Attention split-K partials overlay regions that are DEAD during
    // flash+merge: Opart over Xb (rewritten by add_ln before next read),
    // Mpart/Lpart over Pb (written by O-proj after merge).
    unsigned short* Opart = (unsigned short*)(ws + (16u << 20));   // 512*8192 bf16 = 8 MB
    float* Mpart = (float*)(ws + (24u << 20));                     // 512*64 f32
    float* Lpart = Mpart + 512 * 64;
    unsigned short* in_wb  = (unsigned short*)(ws + (72u << 20));
    unsigned short* out_wb = in_wb  + 3u * 1536 * 512;
    unsigned short* ff1_wb = out_wb + 3u * 512 * 512;
    unsigned short* ff2_wb = ff1_wb + 3u * 2048 * 512;
    float* outp = (float*)d_out;
    const int M = 4 * S_LEN;   // 8192

    conv_all<<<9216, 256, 0, stream>>>(
        (const float4*)in_w, (const float4*)out_w,
        (const float4*)ff1_w, (const float4*)ff2_w,
        (u16x4*)in_wb, (u16x4*)out_wb, (u16x4*)ff1_wb, (u16x4*)ff2_wb);

    embed_kernel<<<M, 256, 0, stream>>>(src, emb_w, emb_b, X, Xb);

    for (int l = 0; l < 3; l++) {
        gemm_bf16<3, 128><<<dim3(768), 256, 0, stream>>>(
            Xb, 512, in_wb + (size_t)l * 1536 * 512, 512, in_b + l * 1536,
            QKb, 1024, Vt, 12);
        flash_attn<<<768, 256, 0, stream>>>(QKb, Vt, Ob, Opart, Mpart, Lpart);
        attn_merge<<<256, 256, 0, stream>>>(Opart, Mpart, Lpart, Ob);
        gemm_bf16<1, 64><<<dim3(512), 256, 0, stream>>>(
            Ob, 512, out_wb + (size_t)l * 512 * 512, 512, out_b + l * 512,
            Pb, 512, nullptr, 8);
        add_ln_kernel<<<M / 4, 256, 0, stream>>>(X, Pb, ln1_g + l * 512, ln1_b + l * 512, Xb);
        gemm_bf16<2, 128><<<dim3(1024), 256, 0, stream>>>(
            Xb, 512, ff1_wb + (size_t)l * 2048 * 512, 512, ff1_b + l * 2048,
            Hb, 2048, nullptr, 16);
        gemm_bf16<1, 64><<<dim3(512), 256, 0, stream>>>(
            Hb, 2048, ff2_wb + (size_t)l * 512 * 2048, 2048, ff2_b + l * 512,
            Pb, 512, nullptr, 8);
        add_ln_kernel<<<M / 4, 256, 0, stream>>>(X, Pb, ln2_g + l * 512, ln2_b + l * 512, Xb);
    }

    decoder_kernel<<<M / 4, 256, 0, stream>>>(X, dec_w, dec_b, outp);
}